// Round 3
// baseline (555.917 us; speedup 1.0000x reference)
//
#include <hip/hip_runtime.h>

// CombinedLoss: chamfer(pred,gt) + 0.1*repulsion(pred,k=4) + 0.01*(1 - mean(n_pred . n_gt))
// B=8, N=2048, fp32 in, fp32 scalar out.
// Normals must match np.linalg.eigh's (LAPACK ssyevd) SIGNS point-by-point:
// we emulate ssytd2 + ssteqr + sormtr for 3x3 in fp32, branch-faithfully.

#define NB 8
#define NP 2048
#define KN 16

// ---------------- LAPACK helpers (fp32, faithful) ----------------

__device__ __forceinline__ float f_slapy2(float x, float y) {
    float xa = fabsf(x), ya = fabsf(y);
    float w = fmaxf(xa, ya), zm = fminf(xa, ya);
    if (zm == 0.f) return w;
    float q = zm / w;
    return w * sqrtf(1.f + q * q);
}

// LAPACK >=3.10 slartg convention: c >= 0 always.
__device__ __forceinline__ void f_slartg(float f, float g, float* cs, float* sn, float* r) {
    if (g == 0.f) { *cs = 1.f; *sn = 0.f; *r = f; }
    else if (f == 0.f) { *cs = 0.f; *sn = copysignf(1.f, g); *r = fabsf(g); }
    else {
        float d = sqrtf(__fadd_rn(__fmul_rn(f, f), __fmul_rn(g, g)));
        *cs = fabsf(f) / d;
        *r  = copysignf(d, f);
        *sn = g / *r;
    }
}

__device__ void f_slaev2(float a, float b, float c,
                         float* rt1, float* rt2, float* cs1, float* sn1) {
    float sm = a + c;
    float df = a - c;
    float adf = fabsf(df);
    float tb = b + b;
    float ab = fabsf(tb);
    float acmx, acmn;
    if (fabsf(a) > fabsf(c)) { acmx = a; acmn = c; } else { acmx = c; acmn = a; }
    float rt;
    if (adf > ab)      { float q = ab / adf; rt = adf * sqrtf(1.f + q * q); }
    else if (adf < ab) { float q = adf / ab; rt = ab * sqrtf(1.f + q * q); }
    else               rt = ab * sqrtf(2.f);
    int sgn1;
    if (sm < 0.f) {
        *rt1 = 0.5f * (sm - rt); sgn1 = -1;
        *rt2 = (acmx / *rt1) * acmn - (b / *rt1) * b;
    } else if (sm > 0.f) {
        *rt1 = 0.5f * (sm + rt); sgn1 = 1;
        *rt2 = (acmx / *rt1) * acmn - (b / *rt1) * b;
    } else {
        *rt1 = 0.5f * rt; *rt2 = -0.5f * rt; sgn1 = 1;
    }
    float cs; int sgn2;
    if (df >= 0.f) { cs = df + rt; sgn2 = 1; }
    else           { cs = df - rt; sgn2 = -1; }
    float acs = fabsf(cs);
    if (acs > ab) {
        float ct = -tb / cs;
        *sn1 = 1.f / sqrtf(1.f + ct * ct);
        *cs1 = ct * *sn1;
    } else {
        if (ab == 0.f) { *cs1 = 1.f; *sn1 = 0.f; }
        else {
            float tn = -cs / tb;
            *cs1 = 1.f / sqrtf(1.f + tn * tn);
            *sn1 = tn * *cs1;
        }
    }
    if (sgn1 == sgn2) { float tn = *cs1; *cs1 = -*sn1; *sn1 = tn; }
}

// fp32 ssyevd for a 3x3 symmetric matrix (lower triangle given), returns
// eigenvector of the SMALLEST eigenvalue, with LAPACK's sign convention.
__device__ void ssyevd3_evec0(float a00, float a10, float a20,
                              float a11, float a21, float a22,
                              float* ox, float* oy, float* oz) {
    // ---- ssytd2('L'): one Householder reflector on (a10, a20) ----
    float d[3], e[2];
    float tau = 0.f, v2 = 0.f;
    float xnorm = fabsf(a20);
    if (xnorm == 0.f) {
        tau = 0.f;
        d[0] = a00; d[1] = a11; d[2] = a22; e[0] = a10; e[1] = a21;
    } else {
        float beta = -copysignf(f_slapy2(a10, xnorm), a10);
        tau = (beta - a10) / beta;
        float inv = 1.f / (a10 - beta);
        v2 = a20 * inv;
        float x1 = tau * (a11 + a21 * v2);
        float x2 = tau * (a21 + a22 * v2);
        float alpha = -0.5f * tau * (x1 + x2 * v2);
        float w1 = x1 + alpha;
        float w2 = x2 + alpha * v2;
        float b11 = a11 - 2.f * w1;
        float b21 = a21 - v2 * w1 - w2;
        float b22 = a22 - 2.f * (v2 * w2);
        d[0] = a00; d[1] = b11; d[2] = b22; e[0] = beta; e[1] = b21;
    }
    // ---- ssteqr('I', n=3) ----
    const float eps    = 5.9604645e-08f;          // 2^-24
    const float eps2   = eps * eps;
    const float safmin = 1.1754944e-38f;
    const float ssfmax = sqrtf(1.f / safmin) / 3.f;
    const float ssfmin = sqrtf(safmin) / eps2;
    const int n = 3, nmaxit = 90;
    float z[3][3] = {{1.f,0.f,0.f},{0.f,1.f,0.f},{0.f,0.f,1.f}};
    int jtot = 0;
    int l1 = 1;

    while (true) {
        if (l1 > n) break;
        if (l1 > 1) e[l1 - 2] = 0.f;
        int m = n;
        for (int mi = l1; mi <= n - 1; ++mi) {
            float tst = fabsf(e[mi - 1]);
            if (tst == 0.f) { m = mi; break; }
            if (tst <= (sqrtf(fabsf(d[mi - 1])) * sqrtf(fabsf(d[mi]))) * eps) {
                e[mi - 1] = 0.f; m = mi; break;
            }
        }
        int l = l1, lsv = l, lend = m, lendsv = lend;
        l1 = m + 1;
        if (lend == l) continue;

        float anorm = 0.f;
        for (int i = l; i <= lend; ++i) anorm = fmaxf(anorm, fabsf(d[i - 1]));
        for (int i = l; i <= lend - 1; ++i) anorm = fmaxf(anorm, fabsf(e[i - 1]));
        int iscale = 0; float sclto = 1.f;
        if (anorm == 0.f) continue;
        if (anorm > ssfmax) { iscale = 1; sclto = ssfmax; }
        else if (anorm < ssfmin) { iscale = 2; sclto = ssfmin; }
        if (iscale) {
            float mul = sclto / anorm;
            for (int i = l; i <= lend; ++i) d[i - 1] *= mul;
            for (int i = l; i <= lend - 1; ++i) e[i - 1] *= mul;
        }
        if (fabsf(d[lend - 1]) < fabsf(d[l - 1])) { lend = lsv; l = lendsv; }

        if (lend > l) {
            // ---- QL iteration ----
            while (true) {
                int mq = lend;
                if (l != lend) {
                    for (int i = l; i <= lend - 1; ++i) {
                        float ei = e[i - 1];
                        float tst = ei * ei;
                        if (tst <= (eps2 * fabsf(d[i - 1])) * fabsf(d[i]) + safmin) { mq = i; break; }
                    }
                }
                if (mq < lend) e[mq - 1] = 0.f;
                float p = d[l - 1];
                if (mq == l) { d[l - 1] = p; l = l + 1; if (l <= lend) continue; break; }
                if (mq == l + 1) {
                    float rt1, rt2, c, s;
                    f_slaev2(d[l - 1], e[l - 1], d[l], &rt1, &rt2, &c, &s);
                    for (int i = 0; i < 3; ++i) {          // dlasr 'B', one rotation on cols (l, l+1)
                        float temp = z[i][l];
                        z[i][l]     = c * temp - s * z[i][l - 1];
                        z[i][l - 1] = s * temp + c * z[i][l - 1];
                    }
                    d[l - 1] = rt1; d[l] = rt2; e[l - 1] = 0.f;
                    l += 2; if (l <= lend) continue; break;
                }
                if (jtot == nmaxit) break;
                jtot++;
                float g = (d[l] - p) / (2.f * e[l - 1]);
                float r = f_slapy2(g, 1.f);
                g = d[mq - 1] - p + e[l - 1] / (g + copysignf(r, g));
                float s = 1.f, c = 1.f; p = 0.f;
                float cw[2], sw[2];
                for (int i = mq - 1; i >= l; --i) {
                    float f = s * e[i - 1];
                    float b = c * e[i - 1];
                    f_slartg(g, f, &c, &s, &r);
                    if (i != mq - 1) e[i] = r;
                    g = d[i] - p;
                    r = (d[i - 1] - g) * s + 2.f * c * b;
                    p = s * r;
                    d[i] = g + p;
                    g = c * r - b;
                    cw[i - l] = c; sw[i - l] = -s;
                }
                for (int j = mq - l; j >= 1; --j) {        // dlasr 'R','V','B'
                    float cj = cw[j - 1], sj = sw[j - 1];
                    int c0 = l - 1 + (j - 1);
                    for (int i = 0; i < 3; ++i) {
                        float temp = z[i][c0 + 1];
                        z[i][c0 + 1] = cj * temp - sj * z[i][c0];
                        z[i][c0]     = sj * temp + cj * z[i][c0];
                    }
                }
                d[l - 1] -= p;
                e[l - 1] = g;
            }
        } else {
            // ---- QR iteration ----
            while (true) {
                int mq = lend;
                if (l != lend) {
                    for (int i = l; i >= lend + 1; --i) {
                        float ei = e[i - 2];
                        float tst = ei * ei;
                        if (tst <= (eps2 * fabsf(d[i - 1])) * fabsf(d[i - 2]) + safmin) { mq = i; break; }
                    }
                }
                if (mq > lend) e[mq - 2] = 0.f;
                float p = d[l - 1];
                if (mq == l) { d[l - 1] = p; l = l - 1; if (l >= lend) continue; break; }
                if (mq == l - 1) {
                    float rt1, rt2, c, s;
                    f_slaev2(d[l - 2], e[l - 2], d[l - 1], &rt1, &rt2, &c, &s);
                    for (int i = 0; i < 3; ++i) {          // dlasr 'F', one rotation on cols (l-1, l)
                        float temp = z[i][l - 1];
                        z[i][l - 1] = c * temp - s * z[i][l - 2];
                        z[i][l - 2] = s * temp + c * z[i][l - 2];
                    }
                    d[l - 2] = rt1; d[l - 1] = rt2; e[l - 2] = 0.f;
                    l -= 2; if (l >= lend) continue; break;
                }
                if (jtot == nmaxit) break;
                jtot++;
                float g = (d[l - 2] - p) / (2.f * e[l - 2]);
                float r = f_slapy2(g, 1.f);
                g = d[mq - 1] - p + e[l - 2] / (g + copysignf(r, g));
                float s = 1.f, c = 1.f; p = 0.f;
                float cw[2], sw[2];
                for (int i = mq; i <= l - 1; ++i) {
                    float f = s * e[i - 1];
                    float b = c * e[i - 1];
                    f_slartg(g, f, &c, &s, &r);
                    if (i != mq) e[i - 2] = r;
                    g = d[i - 1] - p;
                    r = (d[i] - g) * s + 2.f * c * b;
                    p = s * r;
                    d[i - 1] = g + p;
                    g = c * r - b;
                    cw[i - mq] = c; sw[i - mq] = s;
                }
                for (int j = 1; j <= l - mq; ++j) {        // dlasr 'R','V','F'
                    float cj = cw[j - 1], sj = sw[j - 1];
                    int c0 = mq - 1 + (j - 1);
                    for (int i = 0; i < 3; ++i) {
                        float temp = z[i][c0 + 1];
                        z[i][c0 + 1] = cj * temp - sj * z[i][c0];
                        z[i][c0]     = sj * temp + cj * z[i][c0];
                    }
                }
                d[l - 1] -= p;
                e[l - 2] = g;
            }
        }
        if (iscale) {
            float mul = anorm / sclto;
            for (int i = lsv; i <= lendsv; ++i) d[i - 1] *= mul;
            for (int i = lsv; i <= lendsv - 1; ++i) e[i - 1] *= mul;
        }
        if (jtot >= nmaxit) break;
    }

    // ---- sort ascending (selection sort, column swaps — no sign change) ----
    for (int ii = 2; ii <= 3; ++ii) {
        int i = ii - 1, k = i;
        float p = d[i - 1];
        for (int j = ii; j <= 3; ++j) if (d[j - 1] < p) { k = j; p = d[j - 1]; }
        if (k != i) {
            d[k - 1] = d[i - 1]; d[i - 1] = p;
            for (int r = 0; r < 3; ++r) { float t = z[r][i - 1]; z[r][i - 1] = z[r][k - 1]; z[r][k - 1] = t; }
        }
    }
    // ---- sormtr('L','L','N'): apply H to rows 2..3 of column 0 ----
    float r0 = z[0][0], r1 = z[1][0], r2 = z[2][0];
    if (tau != 0.f) {
        float sum = r1 + v2 * r2;
        r1 -= tau * sum;
        r2 -= tau * (v2 * sum);
    }
    *ox = r0; *oy = r1; *oz = r2;
}

// ---------------- scan kernel ----------------
// 512 blocks x 64 threads:
//   blocks [0,256):  home=pred -> top16 on pred (rep + pred normal), min over gt  (chamfer p->g)
//   blocks [256,512): home=gt  -> top16 on gt (gt normal),           min over pred (chamfer g->p)
// d2 for top-16 uses the reference's form: xx + yy - 2*x.y (fp32, sequential
// association, no fma) so the neighbor SET matches np's; self-d2 is exactly 0.

__device__ __forceinline__ float dot_rn(float ax, float ay, float az,
                                        float bx, float by, float bz) {
    return __fadd_rn(__fadd_rn(__fmul_rn(ax, bx), __fmul_rn(ay, by)), __fmul_rn(az, bz));
}

__global__ __launch_bounds__(64) void scan_kernel(
    const float* __restrict__ pred, const float* __restrict__ gt,
    float* __restrict__ nP, float* __restrict__ nG, double* __restrict__ acc)
{
    __shared__ float sh[6][NP];    // [0..2]=home xyz  [3..5]=other xyz (48 KB)
    __shared__ float shyy[NP];     // home squared norms (8 KB)

    int bi = blockIdx.x;
    bool predHome = bi < NB * 32;
    int lb = predHome ? bi : bi - NB * 32;
    int b = lb >> 5;
    int tile = lb & 31;
    int tid = threadIdx.x;

    const float* home  = (predHome ? pred : gt) + (size_t)b * NP * 3;
    const float* other = (predHome ? gt : pred) + (size_t)b * NP * 3;

    for (int t = tid; t < NP * 3; t += 64) {
        int p = t / 3, c = t - p * 3;
        sh[c][p]     = home[t];
        sh[3 + c][p] = other[t];
    }
    __syncthreads();
    for (int j = tid; j < NP; j += 64)
        shyy[j] = dot_rn(sh[0][j], sh[1][j], sh[2][j], sh[0][j], sh[1][j], sh[2][j]);
    __syncthreads();

    int i = tile * 64 + tid;
    float qx = sh[0][i], qy = sh[1][i], qz = sh[2][i];
    float qq = shyy[i];

    unsigned keys[KN];
    #pragma unroll
    for (int s = 0; s < KN; ++s) keys[s] = 0x7F800000u | (unsigned)s;
    unsigned kmax = 0x7F800000u | 15u;

    float minv = 1e30f;

    for (int j = 0; j < NP; ++j) {
        // home candidate (ref-style d2) -> top-16
        float hx = sh[0][j], hy = sh[1][j], hz = sh[2][j];
        float dotj = dot_rn(qx, qy, qz, hx, hy, hz);
        float d2 = __fsub_rn(__fadd_rn(qq, shyy[j]), __fmul_rn(2.f, dotj));
        unsigned key = (__float_as_uint(d2) & 0xFFFFF800u) | (unsigned)j;
        if (key < kmax) {
            #pragma unroll
            for (int s = 0; s < KN; ++s) keys[s] = (keys[s] == kmax) ? key : keys[s];
            unsigned m = keys[0];
            #pragma unroll
            for (int s = 1; s < KN; ++s) m = keys[s] > m ? keys[s] : m;
            kmax = m;
        }
        // other-cloud candidate -> chamfer min (value only; fast form)
        float ox = sh[3][j], oy = sh[4][j], oz = sh[5][j];
        float ex = qx - ox, ey = qy - oy, ez = qz - oz;
        float e2 = fmaf(ex, ex, fmaf(ey, ey, ez * ez));
        minv = fminf(minv, e2);
    }

    // --- covariance over the 16-NN (two-pass centered, /16 like ref) ---
    float sx = 0.f, sy = 0.f, sz = 0.f;
    #pragma unroll
    for (int s = 0; s < KN; ++s) {
        int idx = (int)(keys[s] & 0x7FFu);
        sx += sh[0][idx]; sy += sh[1][idx]; sz += sh[2][idx];
    }
    float mx = sx * (1.0f / KN), my = sy * (1.0f / KN), mz = sz * (1.0f / KN);
    float cxx = 0.f, cxy = 0.f, cxz = 0.f, cyy = 0.f, cyz = 0.f, czz = 0.f;
    #pragma unroll
    for (int s = 0; s < KN; ++s) {
        int idx = (int)(keys[s] & 0x7FFu);
        float ax = sh[0][idx] - mx, ay = sh[1][idx] - my, az = sh[2][idx] - mz;
        cxx += ax * ax; cxy += ax * ay; cxz += ax * az;
        cyy += ay * ay; cyz += ay * az; czz += az * az;
    }
    cxx *= (1.f / KN); cxy *= (1.f / KN); cxz *= (1.f / KN);
    cyy *= (1.f / KN); cyz *= (1.f / KN); czz *= (1.f / KN);

    // --- repulsion: 4 nearest excluding self (pred side only); destroys keys ---
    float rep = 0.0f;
    if (predHome) {
        #pragma unroll
        for (int r = 0; r < 5; ++r) {
            unsigned m = keys[0];
            #pragma unroll
            for (int s = 1; s < KN; ++s) m = keys[s] < m ? keys[s] : m;
            if (r > 0) {
                float d2 = __uint_as_float(m & 0xFFFFF800u);
                float dd = sqrtf(fmaxf(d2, 1e-12f));
                rep += fmaxf(0.02f - dd, 0.0f);
            }
            #pragma unroll
            for (int s = 0; s < KN; ++s) keys[s] = (keys[s] == m) ? 0xFFFFFFFFu : keys[s];
        }
    }

    // --- normal via faithful ssyevd emulation (matches np's signs) ---
    float nx, ny, nz;
    ssyevd3_evec0(cxx, cxy, cxz, cyy, cyz, czz, &nx, &ny, &nz);

    float* nout = predHome ? nP : nG;
    int gi = b * NP + i;
    nout[gi * 3 + 0] = nx;
    nout[gi * 3 + 1] = ny;
    nout[gi * 3 + 2] = nz;

    double part = (double)minv * (1.0 / (NB * NP))
                + (double)rep  * (0.1 / (NB * NP * 4));

    #pragma unroll
    for (int off = 32; off > 0; off >>= 1) part += __shfl_down(part, off);
    if (tid == 0) atomicAdd(acc, part);
}

// ---------------------------------------------------------------------------
__global__ __launch_bounds__(256) void dot_kernel(
    const float* __restrict__ nP, const float* __restrict__ nG, double* __restrict__ acc)
{
    int i = blockIdx.x * 256 + threadIdx.x;
    float d = nP[i * 3] * nG[i * 3] + nP[i * 3 + 1] * nG[i * 3 + 1] + nP[i * 3 + 2] * nG[i * 3 + 2];
    double part = (double)d * (-0.01 / (NB * NP));
    #pragma unroll
    for (int off = 32; off > 0; off >>= 1) part += __shfl_down(part, off);
    if ((threadIdx.x & 63) == 0) atomicAdd(acc, part);
}

__global__ void fin_kernel(const double* __restrict__ acc, float* __restrict__ out)
{
    out[0] = (float)(acc[0] + 0.01);
}

// ---------------------------------------------------------------------------
extern "C" void kernel_launch(void* const* d_in, const int* in_sizes, int n_in,
                              void* d_out, int out_size, void* d_ws, size_t ws_size,
                              hipStream_t stream)
{
    const float* pred = (const float*)d_in[0];
    const float* gt   = (const float*)d_in[1];

    double* acc = (double*)d_ws;
    float* nP = (float*)((char*)d_ws + 64);
    float* nG = (float*)((char*)d_ws + 64 + (size_t)NB * NP * 3 * sizeof(float));

    hipMemsetAsync(d_ws, 0, 64, stream);
    scan_kernel<<<dim3(NB * 32 * 2), dim3(64), 0, stream>>>(pred, gt, nP, nG, acc);
    dot_kernel<<<dim3(NB * NP / 256), dim3(256), 0, stream>>>(nP, nG, acc);
    fin_kernel<<<dim3(1), dim3(1), 0, stream>>>(acc, (float*)d_out);
}

// Round 4
// 230.555 us; speedup vs baseline: 2.4112x; 2.4112x over previous
//
#include <hip/hip_runtime.h>

// CombinedLoss: chamfer(pred,gt) + 0.1*repulsion(pred,k=4) + 0.01*(1 - mean(n_pred . n_gt))
// B=8, N=2048, fp32 in, fp32 scalar out.
// Normals match np.linalg.eigh (LAPACK ssyevd) signs point-by-point via faithful
// fp32 ssytd2+ssteqr+sormtr emulation (R3: absmax 0.0).
// R4: occupancy fix — 256-thr blocks, 4-way candidate split, float4 LDS staging.

#define NB 8
#define NP 2048
#define KN 16

// ---------------- LAPACK helpers (fp32, faithful — DO NOT TOUCH) ----------------

__device__ __forceinline__ float f_slapy2(float x, float y) {
    float xa = fabsf(x), ya = fabsf(y);
    float w = fmaxf(xa, ya), zm = fminf(xa, ya);
    if (zm == 0.f) return w;
    float q = zm / w;
    return w * sqrtf(1.f + q * q);
}

// LAPACK >=3.10 slartg convention: c >= 0 always.
__device__ __forceinline__ void f_slartg(float f, float g, float* cs, float* sn, float* r) {
    if (g == 0.f) { *cs = 1.f; *sn = 0.f; *r = f; }
    else if (f == 0.f) { *cs = 0.f; *sn = copysignf(1.f, g); *r = fabsf(g); }
    else {
        float d = sqrtf(__fadd_rn(__fmul_rn(f, f), __fmul_rn(g, g)));
        *cs = fabsf(f) / d;
        *r  = copysignf(d, f);
        *sn = g / *r;
    }
}

__device__ void f_slaev2(float a, float b, float c,
                         float* rt1, float* rt2, float* cs1, float* sn1) {
    float sm = a + c;
    float df = a - c;
    float adf = fabsf(df);
    float tb = b + b;
    float ab = fabsf(tb);
    float acmx, acmn;
    if (fabsf(a) > fabsf(c)) { acmx = a; acmn = c; } else { acmx = c; acmn = a; }
    float rt;
    if (adf > ab)      { float q = ab / adf; rt = adf * sqrtf(1.f + q * q); }
    else if (adf < ab) { float q = adf / ab; rt = ab * sqrtf(1.f + q * q); }
    else               rt = ab * sqrtf(2.f);
    int sgn1;
    if (sm < 0.f) {
        *rt1 = 0.5f * (sm - rt); sgn1 = -1;
        *rt2 = (acmx / *rt1) * acmn - (b / *rt1) * b;
    } else if (sm > 0.f) {
        *rt1 = 0.5f * (sm + rt); sgn1 = 1;
        *rt2 = (acmx / *rt1) * acmn - (b / *rt1) * b;
    } else {
        *rt1 = 0.5f * rt; *rt2 = -0.5f * rt; sgn1 = 1;
    }
    float cs; int sgn2;
    if (df >= 0.f) { cs = df + rt; sgn2 = 1; }
    else           { cs = df - rt; sgn2 = -1; }
    float acs = fabsf(cs);
    if (acs > ab) {
        float ct = -tb / cs;
        *sn1 = 1.f / sqrtf(1.f + ct * ct);
        *cs1 = ct * *sn1;
    } else {
        if (ab == 0.f) { *cs1 = 1.f; *sn1 = 0.f; }
        else {
            float tn = -cs / tb;
            *cs1 = 1.f / sqrtf(1.f + tn * tn);
            *sn1 = tn * *cs1;
        }
    }
    if (sgn1 == sgn2) { float tn = *cs1; *cs1 = -*sn1; *sn1 = tn; }
}

// fp32 ssyevd for a 3x3 symmetric matrix (lower triangle given), returns
// eigenvector of the SMALLEST eigenvalue, with LAPACK's sign convention.
__device__ void ssyevd3_evec0(float a00, float a10, float a20,
                              float a11, float a21, float a22,
                              float* ox, float* oy, float* oz) {
    // ---- ssytd2('L'): one Householder reflector on (a10, a20) ----
    float d[3], e[2];
    float tau = 0.f, v2 = 0.f;
    float xnorm = fabsf(a20);
    if (xnorm == 0.f) {
        tau = 0.f;
        d[0] = a00; d[1] = a11; d[2] = a22; e[0] = a10; e[1] = a21;
    } else {
        float beta = -copysignf(f_slapy2(a10, xnorm), a10);
        tau = (beta - a10) / beta;
        float inv = 1.f / (a10 - beta);
        v2 = a20 * inv;
        float x1 = tau * (a11 + a21 * v2);
        float x2 = tau * (a21 + a22 * v2);
        float alpha = -0.5f * tau * (x1 + x2 * v2);
        float w1 = x1 + alpha;
        float w2 = x2 + alpha * v2;
        float b11 = a11 - 2.f * w1;
        float b21 = a21 - v2 * w1 - w2;
        float b22 = a22 - 2.f * (v2 * w2);
        d[0] = a00; d[1] = b11; d[2] = b22; e[0] = beta; e[1] = b21;
    }
    // ---- ssteqr('I', n=3) ----
    const float eps    = 5.9604645e-08f;          // 2^-24
    const float eps2   = eps * eps;
    const float safmin = 1.1754944e-38f;
    const float ssfmax = sqrtf(1.f / safmin) / 3.f;
    const float ssfmin = sqrtf(safmin) / eps2;
    const int n = 3, nmaxit = 90;
    float z[3][3] = {{1.f,0.f,0.f},{0.f,1.f,0.f},{0.f,0.f,1.f}};
    int jtot = 0;
    int l1 = 1;

    while (true) {
        if (l1 > n) break;
        if (l1 > 1) e[l1 - 2] = 0.f;
        int m = n;
        for (int mi = l1; mi <= n - 1; ++mi) {
            float tst = fabsf(e[mi - 1]);
            if (tst == 0.f) { m = mi; break; }
            if (tst <= (sqrtf(fabsf(d[mi - 1])) * sqrtf(fabsf(d[mi]))) * eps) {
                e[mi - 1] = 0.f; m = mi; break;
            }
        }
        int l = l1, lsv = l, lend = m, lendsv = lend;
        l1 = m + 1;
        if (lend == l) continue;

        float anorm = 0.f;
        for (int i = l; i <= lend; ++i) anorm = fmaxf(anorm, fabsf(d[i - 1]));
        for (int i = l; i <= lend - 1; ++i) anorm = fmaxf(anorm, fabsf(e[i - 1]));
        int iscale = 0; float sclto = 1.f;
        if (anorm == 0.f) continue;
        if (anorm > ssfmax) { iscale = 1; sclto = ssfmax; }
        else if (anorm < ssfmin) { iscale = 2; sclto = ssfmin; }
        if (iscale) {
            float mul = sclto / anorm;
            for (int i = l; i <= lend; ++i) d[i - 1] *= mul;
            for (int i = l; i <= lend - 1; ++i) e[i - 1] *= mul;
        }
        if (fabsf(d[lend - 1]) < fabsf(d[l - 1])) { lend = lsv; l = lendsv; }

        if (lend > l) {
            // ---- QL iteration ----
            while (true) {
                int mq = lend;
                if (l != lend) {
                    for (int i = l; i <= lend - 1; ++i) {
                        float ei = e[i - 1];
                        float tst = ei * ei;
                        if (tst <= (eps2 * fabsf(d[i - 1])) * fabsf(d[i]) + safmin) { mq = i; break; }
                    }
                }
                if (mq < lend) e[mq - 1] = 0.f;
                float p = d[l - 1];
                if (mq == l) { d[l - 1] = p; l = l + 1; if (l <= lend) continue; break; }
                if (mq == l + 1) {
                    float rt1, rt2, c, s;
                    f_slaev2(d[l - 1], e[l - 1], d[l], &rt1, &rt2, &c, &s);
                    for (int i = 0; i < 3; ++i) {
                        float temp = z[i][l];
                        z[i][l]     = c * temp - s * z[i][l - 1];
                        z[i][l - 1] = s * temp + c * z[i][l - 1];
                    }
                    d[l - 1] = rt1; d[l] = rt2; e[l - 1] = 0.f;
                    l += 2; if (l <= lend) continue; break;
                }
                if (jtot == nmaxit) break;
                jtot++;
                float g = (d[l] - p) / (2.f * e[l - 1]);
                float r = f_slapy2(g, 1.f);
                g = d[mq - 1] - p + e[l - 1] / (g + copysignf(r, g));
                float s = 1.f, c = 1.f; p = 0.f;
                float cw[2], sw[2];
                for (int i = mq - 1; i >= l; --i) {
                    float f = s * e[i - 1];
                    float b = c * e[i - 1];
                    f_slartg(g, f, &c, &s, &r);
                    if (i != mq - 1) e[i] = r;
                    g = d[i] - p;
                    r = (d[i - 1] - g) * s + 2.f * c * b;
                    p = s * r;
                    d[i] = g + p;
                    g = c * r - b;
                    cw[i - l] = c; sw[i - l] = -s;
                }
                for (int j = mq - l; j >= 1; --j) {
                    float cj = cw[j - 1], sj = sw[j - 1];
                    int c0 = l - 1 + (j - 1);
                    for (int i = 0; i < 3; ++i) {
                        float temp = z[i][c0 + 1];
                        z[i][c0 + 1] = cj * temp - sj * z[i][c0];
                        z[i][c0]     = sj * temp + cj * z[i][c0];
                    }
                }
                d[l - 1] -= p;
                e[l - 1] = g;
            }
        } else {
            // ---- QR iteration ----
            while (true) {
                int mq = lend;
                if (l != lend) {
                    for (int i = l; i >= lend + 1; --i) {
                        float ei = e[i - 2];
                        float tst = ei * ei;
                        if (tst <= (eps2 * fabsf(d[i - 1])) * fabsf(d[i - 2]) + safmin) { mq = i; break; }
                    }
                }
                if (mq > lend) e[mq - 2] = 0.f;
                float p = d[l - 1];
                if (mq == l) { d[l - 1] = p; l = l - 1; if (l >= lend) continue; break; }
                if (mq == l - 1) {
                    float rt1, rt2, c, s;
                    f_slaev2(d[l - 2], e[l - 2], d[l - 1], &rt1, &rt2, &c, &s);
                    for (int i = 0; i < 3; ++i) {
                        float temp = z[i][l - 1];
                        z[i][l - 1] = c * temp - s * z[i][l - 2];
                        z[i][l - 2] = s * temp + c * z[i][l - 2];
                    }
                    d[l - 2] = rt1; d[l - 1] = rt2; e[l - 2] = 0.f;
                    l -= 2; if (l >= lend) continue; break;
                }
                if (jtot == nmaxit) break;
                jtot++;
                float g = (d[l - 2] - p) / (2.f * e[l - 2]);
                float r = f_slapy2(g, 1.f);
                g = d[mq - 1] - p + e[l - 2] / (g + copysignf(r, g));
                float s = 1.f, c = 1.f; p = 0.f;
                float cw[2], sw[2];
                for (int i = mq; i <= l - 1; ++i) {
                    float f = s * e[i - 1];
                    float b = c * e[i - 1];
                    f_slartg(g, f, &c, &s, &r);
                    if (i != mq) e[i - 2] = r;
                    g = d[i - 1] - p;
                    r = (d[i] - g) * s + 2.f * c * b;
                    p = s * r;
                    d[i - 1] = g + p;
                    g = c * r - b;
                    cw[i - mq] = c; sw[i - mq] = s;
                }
                for (int j = 1; j <= l - mq; ++j) {
                    float cj = cw[j - 1], sj = sw[j - 1];
                    int c0 = mq - 1 + (j - 1);
                    for (int i = 0; i < 3; ++i) {
                        float temp = z[i][c0 + 1];
                        z[i][c0 + 1] = cj * temp - sj * z[i][c0];
                        z[i][c0]     = sj * temp + cj * z[i][c0];
                    }
                }
                d[l - 1] -= p;
                e[l - 2] = g;
            }
        }
        if (iscale) {
            float mul = anorm / sclto;
            for (int i = lsv; i <= lendsv; ++i) d[i - 1] *= mul;
            for (int i = lsv; i <= lendsv - 1; ++i) e[i - 1] *= mul;
        }
        if (jtot >= nmaxit) break;
    }

    // ---- sort ascending (selection sort, column swaps — no sign change) ----
    for (int ii = 2; ii <= 3; ++ii) {
        int i = ii - 1, k = i;
        float p = d[i - 1];
        for (int j = ii; j <= 3; ++j) if (d[j - 1] < p) { k = j; p = d[j - 1]; }
        if (k != i) {
            d[k - 1] = d[i - 1]; d[i - 1] = p;
            for (int r = 0; r < 3; ++r) { float t = z[r][i - 1]; z[r][i - 1] = z[r][k - 1]; z[r][k - 1] = t; }
        }
    }
    // ---- sormtr('L','L','N') ----
    float r0 = z[0][0], r1 = z[1][0], r2 = z[2][0];
    if (tau != 0.f) {
        float sum = r1 + v2 * r2;
        r1 -= tau * sum;
        r2 -= tau * (v2 * sum);
    }
    *ox = r0; *oy = r1; *oz = r2;
}

// ---------------- scan kernel ----------------
// 512 blocks x 256 threads (4 waves).
//   blocks [0,256):  home=pred -> top16 on pred (rep + pred normal), min over gt
//   blocks [256,512): home=gt  -> top16 on gt (gt normal),           min over pred
// All 4 waves serve the SAME 64 queries (tile), each scanning a 512-candidate
// slice; partial top-16s (distinct packed keys -> merge-order-invariant set)
// and partial chamfer mins merge through LDS; wave 0 does the tail.
// d2 formula matches the reference bit-exactly: (qq + cn) - 2*dot, dot_rn.

__device__ __forceinline__ float dot_rn(float ax, float ay, float az,
                                        float bx, float by, float bz) {
    return __fadd_rn(__fadd_rn(__fmul_rn(ax, bx), __fmul_rn(ay, by)), __fmul_rn(az, bz));
}

__global__ __launch_bounds__(256) void scan_kernel(
    const float* __restrict__ pred, const float* __restrict__ gt,
    float* __restrict__ nP, float* __restrict__ nG, double* __restrict__ acc)
{
    __shared__ float4 sHome[NP];   // (x,y,z,|p|^2)  32 KB
    __shared__ float4 sOther[NP];  // (x,y,z,0)      32 KB — reused post-scan for merge
    unsigned* kbuf = (unsigned*)sOther;              // [4][64][16] uints = 16 KB
    float*    mbuf = (float*)sOther + 4096;          // [4][64] floats = 1 KB

    int bi = blockIdx.x;
    bool predHome = bi < NB * 32;
    int lb = predHome ? bi : bi - NB * 32;
    int b = lb >> 5;
    int tile = lb & 31;
    int tid  = threadIdx.x;
    int wave = tid >> 6;
    int lane = tid & 63;

    const float* home  = (predHome ? pred : gt) + (size_t)b * NP * 3;
    const float* other = (predHome ? gt : pred) + (size_t)b * NP * 3;

    for (int j = tid; j < NP; j += 256) {
        float hx = home[3 * j], hy = home[3 * j + 1], hz = home[3 * j + 2];
        sHome[j] = make_float4(hx, hy, hz, dot_rn(hx, hy, hz, hx, hy, hz));
        float ox = other[3 * j], oy = other[3 * j + 1], oz = other[3 * j + 2];
        sOther[j] = make_float4(ox, oy, oz, 0.f);
    }
    __syncthreads();

    int i = tile * 64 + lane;
    float4 q = sHome[i];
    float qx = q.x, qy = q.y, qz = q.z, qq = q.w;

    unsigned keys[KN];
    #pragma unroll
    for (int s = 0; s < KN; ++s) keys[s] = 0x7F800000u | (unsigned)s;  // distinct "inf" seeds
    unsigned kmax = 0x7F800000u | 15u;

    float minv = 1e30f;

    int jlo = wave * (NP / 4), jhi = jlo + (NP / 4);
    for (int j = jlo; j < jhi; ++j) {
        float4 h = sHome[j];                          // broadcast ds_read_b128
        float dotj = dot_rn(qx, qy, qz, h.x, h.y, h.z);
        float d2 = __fsub_rn(__fadd_rn(qq, h.w), __fmul_rn(2.f, dotj));
        unsigned key = (__float_as_uint(d2) & 0xFFFFF800u) | (unsigned)j;
        if (key < kmax) {
            #pragma unroll
            for (int s = 0; s < KN; ++s) keys[s] = (keys[s] == kmax) ? key : keys[s];
            unsigned m = keys[0];
            #pragma unroll
            for (int s = 1; s < KN; ++s) m = keys[s] > m ? keys[s] : m;
            kmax = m;
        }
        float4 o = sOther[j];                         // broadcast ds_read_b128
        float ex = qx - o.x, ey = qy - o.y, ez = qz - o.z;
        minv = fminf(minv, fmaf(ex, ex, fmaf(ey, ey, ez * ez)));
    }
    __syncthreads();   // scan done in all waves before sOther is overwritten

    // publish partials: kbuf[wave][lane][s], mbuf[wave][lane]
    {
        unsigned* kp = kbuf + ((wave * 64 + lane) * KN);
        #pragma unroll
        for (int s = 0; s < KN; ++s) kp[s] = keys[s];
        mbuf[wave * 64 + lane] = minv;
    }
    __syncthreads();

    if (wave != 0) return;   // wave 0 owns the tail; 512 slice >= 16 so all seeds evicted

    // --- merge 4 partial top-16s (sets are disjoint; keys distinct) ---
    {
        const unsigned* kp0 = kbuf + (lane * KN);
        #pragma unroll
        for (int s = 0; s < KN; ++s) keys[s] = kp0[s];
        unsigned m = keys[0];
        #pragma unroll
        for (int s = 1; s < KN; ++s) m = keys[s] > m ? keys[s] : m;
        kmax = m;
        for (int w = 1; w < 4; ++w) {
            const unsigned* kp = kbuf + ((w * 64 + lane) * KN);
            #pragma unroll
            for (int t = 0; t < KN; ++t) {
                unsigned key = kp[t];
                if (key < kmax) {
                    #pragma unroll
                    for (int s = 0; s < KN; ++s) keys[s] = (keys[s] == kmax) ? key : keys[s];
                    unsigned mm = keys[0];
                    #pragma unroll
                    for (int s = 1; s < KN; ++s) mm = keys[s] > mm ? keys[s] : mm;
                    kmax = mm;
                }
            }
        }
        minv = fminf(fminf(mbuf[lane], mbuf[64 + lane]),
                     fminf(mbuf[128 + lane], mbuf[192 + lane]));
    }

    // --- covariance over the 16-NN (two-pass centered, /16 like ref) ---
    float sx = 0.f, sy = 0.f, sz = 0.f;
    #pragma unroll
    for (int s = 0; s < KN; ++s) {
        float4 p = sHome[keys[s] & 0x7FFu];
        sx += p.x; sy += p.y; sz += p.z;
    }
    float mx = sx * (1.0f / KN), my = sy * (1.0f / KN), mz = sz * (1.0f / KN);
    float cxx = 0.f, cxy = 0.f, cxz = 0.f, cyy = 0.f, cyz = 0.f, czz = 0.f;
    #pragma unroll
    for (int s = 0; s < KN; ++s) {
        float4 p = sHome[keys[s] & 0x7FFu];
        float ax = p.x - mx, ay = p.y - my, az = p.z - mz;
        cxx += ax * ax; cxy += ax * ay; cxz += ax * az;
        cyy += ay * ay; cyz += ay * az; czz += az * az;
    }
    cxx *= (1.f / KN); cxy *= (1.f / KN); cxz *= (1.f / KN);
    cyy *= (1.f / KN); cyz *= (1.f / KN); czz *= (1.f / KN);

    // --- repulsion: 4 nearest excluding self (pred side only); destroys keys ---
    float rep = 0.0f;
    if (predHome) {
        #pragma unroll
        for (int r = 0; r < 5; ++r) {
            unsigned m = keys[0];
            #pragma unroll
            for (int s = 1; s < KN; ++s) m = keys[s] < m ? keys[s] : m;
            if (r > 0) {
                float d2 = __uint_as_float(m & 0xFFFFF800u);
                float dd = sqrtf(fmaxf(d2, 1e-12f));
                rep += fmaxf(0.02f - dd, 0.0f);
            }
            #pragma unroll
            for (int s = 0; s < KN; ++s) keys[s] = (keys[s] == m) ? 0xFFFFFFFFu : keys[s];
        }
    }

    // --- normal via faithful ssyevd emulation (matches np's signs) ---
    float nx, ny, nz;
    ssyevd3_evec0(cxx, cxy, cxz, cyy, cyz, czz, &nx, &ny, &nz);

    float* nout = predHome ? nP : nG;
    int gi = b * NP + i;
    nout[gi * 3 + 0] = nx;
    nout[gi * 3 + 1] = ny;
    nout[gi * 3 + 2] = nz;

    double part = (double)minv * (1.0 / (NB * NP))
                + (double)rep  * (0.1 / (NB * NP * 4));

    #pragma unroll
    for (int off = 32; off > 0; off >>= 1) part += __shfl_down(part, off);
    if (lane == 0) atomicAdd(acc, part);
}

// ---------------------------------------------------------------------------
__global__ __launch_bounds__(256) void dot_kernel(
    const float* __restrict__ nP, const float* __restrict__ nG, double* __restrict__ acc)
{
    int i = blockIdx.x * 256 + threadIdx.x;
    float d = nP[i * 3] * nG[i * 3] + nP[i * 3 + 1] * nG[i * 3 + 1] + nP[i * 3 + 2] * nG[i * 3 + 2];
    double part = (double)d * (-0.01 / (NB * NP));
    #pragma unroll
    for (int off = 32; off > 0; off >>= 1) part += __shfl_down(part, off);
    if ((threadIdx.x & 63) == 0) atomicAdd(acc, part);
}

__global__ void fin_kernel(const double* __restrict__ acc, float* __restrict__ out)
{
    out[0] = (float)(acc[0] + 0.01);
}

// ---------------------------------------------------------------------------
extern "C" void kernel_launch(void* const* d_in, const int* in_sizes, int n_in,
                              void* d_out, int out_size, void* d_ws, size_t ws_size,
                              hipStream_t stream)
{
    const float* pred = (const float*)d_in[0];
    const float* gt   = (const float*)d_in[1];

    double* acc = (double*)d_ws;
    float* nP = (float*)((char*)d_ws + 64);
    float* nG = (float*)((char*)d_ws + 64 + (size_t)NB * NP * 3 * sizeof(float));

    hipMemsetAsync(d_ws, 0, 64, stream);
    scan_kernel<<<dim3(NB * 32 * 2), dim3(256), 0, stream>>>(pred, gt, nP, nG, acc);
    dot_kernel<<<dim3(NB * NP / 256), dim3(256), 0, stream>>>(nP, nG, acc);
    fin_kernel<<<dim3(1), dim3(1), 0, stream>>>(acc, (float*)d_out);
}

// Round 5
// 218.372 us; speedup vs baseline: 2.5457x; 1.0558x over previous
//
#include <hip/hip_runtime.h>

// CombinedLoss: chamfer(pred,gt) + 0.1*repulsion(pred,k=4) + 0.01*(1 - mean(n_pred . n_gt))
// B=8, N=2048, fp32 in, fp32 scalar out.
// Normals match np.linalg.eigh (LAPACK ssyevd) signs point-by-point via faithful
// fp32 ssytd2+ssteqr+sormtr emulation (R3/R4: absmax 0.0).
// R5: Morton-sorted scan order (insertion-branch coherence) + 512-thr blocks with
// 8-way interleaved candidate split + tree merge. Keys pack ORIGINAL indices and
// use the identical d2 formula -> selected top-16 sets bit-identical to R4.

#define NB 8
#define NP 2048
#define KN 16

// ---------------- LAPACK helpers (fp32, faithful — DO NOT TOUCH) ----------------

__device__ __forceinline__ float f_slapy2(float x, float y) {
    float xa = fabsf(x), ya = fabsf(y);
    float w = fmaxf(xa, ya), zm = fminf(xa, ya);
    if (zm == 0.f) return w;
    float q = zm / w;
    return w * sqrtf(1.f + q * q);
}

// LAPACK >=3.10 slartg convention: c >= 0 always.
__device__ __forceinline__ void f_slartg(float f, float g, float* cs, float* sn, float* r) {
    if (g == 0.f) { *cs = 1.f; *sn = 0.f; *r = f; }
    else if (f == 0.f) { *cs = 0.f; *sn = copysignf(1.f, g); *r = fabsf(g); }
    else {
        float d = sqrtf(__fadd_rn(__fmul_rn(f, f), __fmul_rn(g, g)));
        *cs = fabsf(f) / d;
        *r  = copysignf(d, f);
        *sn = g / *r;
    }
}

__device__ void f_slaev2(float a, float b, float c,
                         float* rt1, float* rt2, float* cs1, float* sn1) {
    float sm = a + c;
    float df = a - c;
    float adf = fabsf(df);
    float tb = b + b;
    float ab = fabsf(tb);
    float acmx, acmn;
    if (fabsf(a) > fabsf(c)) { acmx = a; acmn = c; } else { acmx = c; acmn = a; }
    float rt;
    if (adf > ab)      { float q = ab / adf; rt = adf * sqrtf(1.f + q * q); }
    else if (adf < ab) { float q = adf / ab; rt = ab * sqrtf(1.f + q * q); }
    else               rt = ab * sqrtf(2.f);
    int sgn1;
    if (sm < 0.f) {
        *rt1 = 0.5f * (sm - rt); sgn1 = -1;
        *rt2 = (acmx / *rt1) * acmn - (b / *rt1) * b;
    } else if (sm > 0.f) {
        *rt1 = 0.5f * (sm + rt); sgn1 = 1;
        *rt2 = (acmx / *rt1) * acmn - (b / *rt1) * b;
    } else {
        *rt1 = 0.5f * rt; *rt2 = -0.5f * rt; sgn1 = 1;
    }
    float cs; int sgn2;
    if (df >= 0.f) { cs = df + rt; sgn2 = 1; }
    else           { cs = df - rt; sgn2 = -1; }
    float acs = fabsf(cs);
    if (acs > ab) {
        float ct = -tb / cs;
        *sn1 = 1.f / sqrtf(1.f + ct * ct);
        *cs1 = ct * *sn1;
    } else {
        if (ab == 0.f) { *cs1 = 1.f; *sn1 = 0.f; }
        else {
            float tn = -cs / tb;
            *cs1 = 1.f / sqrtf(1.f + tn * tn);
            *sn1 = tn * *cs1;
        }
    }
    if (sgn1 == sgn2) { float tn = *cs1; *cs1 = -*sn1; *sn1 = tn; }
}

// fp32 ssyevd for a 3x3 symmetric matrix (lower triangle given), returns
// eigenvector of the SMALLEST eigenvalue, with LAPACK's sign convention.
__device__ void ssyevd3_evec0(float a00, float a10, float a20,
                              float a11, float a21, float a22,
                              float* ox, float* oy, float* oz) {
    // ---- ssytd2('L') ----
    float d[3], e[2];
    float tau = 0.f, v2 = 0.f;
    float xnorm = fabsf(a20);
    if (xnorm == 0.f) {
        tau = 0.f;
        d[0] = a00; d[1] = a11; d[2] = a22; e[0] = a10; e[1] = a21;
    } else {
        float beta = -copysignf(f_slapy2(a10, xnorm), a10);
        tau = (beta - a10) / beta;
        float inv = 1.f / (a10 - beta);
        v2 = a20 * inv;
        float x1 = tau * (a11 + a21 * v2);
        float x2 = tau * (a21 + a22 * v2);
        float alpha = -0.5f * tau * (x1 + x2 * v2);
        float w1 = x1 + alpha;
        float w2 = x2 + alpha * v2;
        float b11 = a11 - 2.f * w1;
        float b21 = a21 - v2 * w1 - w2;
        float b22 = a22 - 2.f * (v2 * w2);
        d[0] = a00; d[1] = b11; d[2] = b22; e[0] = beta; e[1] = b21;
    }
    // ---- ssteqr('I', n=3) ----
    const float eps    = 5.9604645e-08f;
    const float eps2   = eps * eps;
    const float safmin = 1.1754944e-38f;
    const float ssfmax = sqrtf(1.f / safmin) / 3.f;
    const float ssfmin = sqrtf(safmin) / eps2;
    const int n = 3, nmaxit = 90;
    float z[3][3] = {{1.f,0.f,0.f},{0.f,1.f,0.f},{0.f,0.f,1.f}};
    int jtot = 0;
    int l1 = 1;

    while (true) {
        if (l1 > n) break;
        if (l1 > 1) e[l1 - 2] = 0.f;
        int m = n;
        for (int mi = l1; mi <= n - 1; ++mi) {
            float tst = fabsf(e[mi - 1]);
            if (tst == 0.f) { m = mi; break; }
            if (tst <= (sqrtf(fabsf(d[mi - 1])) * sqrtf(fabsf(d[mi]))) * eps) {
                e[mi - 1] = 0.f; m = mi; break;
            }
        }
        int l = l1, lsv = l, lend = m, lendsv = lend;
        l1 = m + 1;
        if (lend == l) continue;

        float anorm = 0.f;
        for (int i = l; i <= lend; ++i) anorm = fmaxf(anorm, fabsf(d[i - 1]));
        for (int i = l; i <= lend - 1; ++i) anorm = fmaxf(anorm, fabsf(e[i - 1]));
        int iscale = 0; float sclto = 1.f;
        if (anorm == 0.f) continue;
        if (anorm > ssfmax) { iscale = 1; sclto = ssfmax; }
        else if (anorm < ssfmin) { iscale = 2; sclto = ssfmin; }
        if (iscale) {
            float mul = sclto / anorm;
            for (int i = l; i <= lend; ++i) d[i - 1] *= mul;
            for (int i = l; i <= lend - 1; ++i) e[i - 1] *= mul;
        }
        if (fabsf(d[lend - 1]) < fabsf(d[l - 1])) { lend = lsv; l = lendsv; }

        if (lend > l) {
            // QL
            while (true) {
                int mq = lend;
                if (l != lend) {
                    for (int i = l; i <= lend - 1; ++i) {
                        float ei = e[i - 1];
                        float tst = ei * ei;
                        if (tst <= (eps2 * fabsf(d[i - 1])) * fabsf(d[i]) + safmin) { mq = i; break; }
                    }
                }
                if (mq < lend) e[mq - 1] = 0.f;
                float p = d[l - 1];
                if (mq == l) { d[l - 1] = p; l = l + 1; if (l <= lend) continue; break; }
                if (mq == l + 1) {
                    float rt1, rt2, c, s;
                    f_slaev2(d[l - 1], e[l - 1], d[l], &rt1, &rt2, &c, &s);
                    for (int i = 0; i < 3; ++i) {
                        float temp = z[i][l];
                        z[i][l]     = c * temp - s * z[i][l - 1];
                        z[i][l - 1] = s * temp + c * z[i][l - 1];
                    }
                    d[l - 1] = rt1; d[l] = rt2; e[l - 1] = 0.f;
                    l += 2; if (l <= lend) continue; break;
                }
                if (jtot == nmaxit) break;
                jtot++;
                float g = (d[l] - p) / (2.f * e[l - 1]);
                float r = f_slapy2(g, 1.f);
                g = d[mq - 1] - p + e[l - 1] / (g + copysignf(r, g));
                float s = 1.f, c = 1.f; p = 0.f;
                float cw[2], sw[2];
                for (int i = mq - 1; i >= l; --i) {
                    float f = s * e[i - 1];
                    float b = c * e[i - 1];
                    f_slartg(g, f, &c, &s, &r);
                    if (i != mq - 1) e[i] = r;
                    g = d[i] - p;
                    r = (d[i - 1] - g) * s + 2.f * c * b;
                    p = s * r;
                    d[i] = g + p;
                    g = c * r - b;
                    cw[i - l] = c; sw[i - l] = -s;
                }
                for (int j = mq - l; j >= 1; --j) {
                    float cj = cw[j - 1], sj = sw[j - 1];
                    int c0 = l - 1 + (j - 1);
                    for (int i = 0; i < 3; ++i) {
                        float temp = z[i][c0 + 1];
                        z[i][c0 + 1] = cj * temp - sj * z[i][c0];
                        z[i][c0]     = sj * temp + cj * z[i][c0];
                    }
                }
                d[l - 1] -= p;
                e[l - 1] = g;
            }
        } else {
            // QR
            while (true) {
                int mq = lend;
                if (l != lend) {
                    for (int i = l; i >= lend + 1; --i) {
                        float ei = e[i - 2];
                        float tst = ei * ei;
                        if (tst <= (eps2 * fabsf(d[i - 1])) * fabsf(d[i - 2]) + safmin) { mq = i; break; }
                    }
                }
                if (mq > lend) e[mq - 2] = 0.f;
                float p = d[l - 1];
                if (mq == l) { d[l - 1] = p; l = l - 1; if (l >= lend) continue; break; }
                if (mq == l - 1) {
                    float rt1, rt2, c, s;
                    f_slaev2(d[l - 2], e[l - 2], d[l - 1], &rt1, &rt2, &c, &s);
                    for (int i = 0; i < 3; ++i) {
                        float temp = z[i][l - 1];
                        z[i][l - 1] = c * temp - s * z[i][l - 2];
                        z[i][l - 2] = s * temp + c * z[i][l - 2];
                    }
                    d[l - 2] = rt1; d[l - 1] = rt2; e[l - 2] = 0.f;
                    l -= 2; if (l >= lend) continue; break;
                }
                if (jtot == nmaxit) break;
                jtot++;
                float g = (d[l - 2] - p) / (2.f * e[l - 2]);
                float r = f_slapy2(g, 1.f);
                g = d[mq - 1] - p + e[l - 2] / (g + copysignf(r, g));
                float s = 1.f, c = 1.f; p = 0.f;
                float cw[2], sw[2];
                for (int i = mq; i <= l - 1; ++i) {
                    float f = s * e[i - 1];
                    float b = c * e[i - 1];
                    f_slartg(g, f, &c, &s, &r);
                    if (i != mq) e[i - 2] = r;
                    g = d[i - 1] - p;
                    r = (d[i] - g) * s + 2.f * c * b;
                    p = s * r;
                    d[i - 1] = g + p;
                    g = c * r - b;
                    cw[i - mq] = c; sw[i - mq] = s;
                }
                for (int j = 1; j <= l - mq; ++j) {
                    float cj = cw[j - 1], sj = sw[j - 1];
                    int c0 = mq - 1 + (j - 1);
                    for (int i = 0; i < 3; ++i) {
                        float temp = z[i][c0 + 1];
                        z[i][c0 + 1] = cj * temp - sj * z[i][c0];
                        z[i][c0]     = sj * temp + cj * z[i][c0];
                    }
                }
                d[l - 1] -= p;
                e[l - 2] = g;
            }
        }
        if (iscale) {
            float mul = anorm / sclto;
            for (int i = lsv; i <= lendsv; ++i) d[i - 1] *= mul;
            for (int i = lsv; i <= lendsv - 1; ++i) e[i - 1] *= mul;
        }
        if (jtot >= nmaxit) break;
    }

    // sort ascending (column swaps — no sign change)
    for (int ii = 2; ii <= 3; ++ii) {
        int i = ii - 1, k = i;
        float p = d[i - 1];
        for (int j = ii; j <= 3; ++j) if (d[j - 1] < p) { k = j; p = d[j - 1]; }
        if (k != i) {
            d[k - 1] = d[i - 1]; d[i - 1] = p;
            for (int r = 0; r < 3; ++r) { float t = z[r][i - 1]; z[r][i - 1] = z[r][k - 1]; z[r][k - 1] = t; }
        }
    }
    // sormtr('L','L','N')
    float r0 = z[0][0], r1 = z[1][0], r2 = z[2][0];
    if (tau != 0.f) {
        float sum = r1 + v2 * r2;
        r1 -= tau * sum;
        r2 -= tau * (v2 * sum);
    }
    *ox = r0; *oy = r1; *oz = r2;
}

// ---------------- common ----------------

__device__ __forceinline__ float dot_rn(float ax, float ay, float az,
                                        float bx, float by, float bz) {
    return __fadd_rn(__fadd_rn(__fmul_rn(ax, bx), __fmul_rn(ay, by)), __fmul_rn(az, bz));
}

__device__ __forceinline__ unsigned spread7(unsigned v) {
    v &= 0x7Fu;
    v = (v | (v << 16)) & 0x030000FFu;
    v = (v | (v << 8))  & 0x0300F00Fu;
    v = (v | (v << 4))  & 0x030C30C3u;
    v = (v | (v << 2))  & 0x09249249u;
    return v;
}

// ---------------- sort kernel ----------------
// 16 blocks (cloud*8+batch) x 1024 threads. Bitonic sort of 2048 u32 keys
// (morton21 << 11 | idx) in LDS; emits morton-ordered float4 (x,y,z,|p|^2)
// and the original-index permutation (u16).
__global__ __launch_bounds__(1024) void sort_kernel(
    const float* __restrict__ pred, const float* __restrict__ gt,
    float4* __restrict__ mort4, unsigned short* __restrict__ midx)
{
    __shared__ unsigned sk[NP];
    int bc = blockIdx.x;
    int cloud = bc >> 3, b = bc & 7;
    const float* src = (cloud ? gt : pred) + (size_t)b * NP * 3;
    int tid = threadIdx.x;

    for (int t = tid; t < NP; t += 1024) {
        float x = src[3 * t], y = src[3 * t + 1], z = src[3 * t + 2];
        unsigned ix = (unsigned)fminf(fmaxf(x, 0.f) * 128.f, 127.f);
        unsigned iy = (unsigned)fminf(fmaxf(y, 0.f) * 128.f, 127.f);
        unsigned iz = (unsigned)fminf(fmaxf(z, 0.f) * 128.f, 127.f);
        unsigned morton = (spread7(ix) << 2) | (spread7(iy) << 1) | spread7(iz);
        sk[t] = (morton << 11) | (unsigned)t;
    }
    __syncthreads();
    for (unsigned k = 2; k <= NP; k <<= 1) {
        for (unsigned j = k >> 1; j > 0; j >>= 1) {
            for (int t = tid; t < NP; t += 1024) {
                unsigned ixj = (unsigned)t ^ j;
                if (ixj > (unsigned)t) {
                    unsigned a = sk[t], c = sk[ixj];
                    bool up = (((unsigned)t & k) == 0);
                    if ((a > c) == up) { sk[t] = c; sk[ixj] = a; }
                }
            }
            __syncthreads();
        }
    }
    float4* out4 = mort4 + (size_t)bc * NP;
    unsigned short* oix = midx + (size_t)bc * NP;
    for (int t = tid; t < NP; t += 1024) {
        unsigned oi = sk[t] & 0x7FFu;
        float x = src[3 * oi], y = src[3 * oi + 1], z = src[3 * oi + 2];
        out4[t] = make_float4(x, y, z, dot_rn(x, y, z, x, y, z));
        oix[t] = (unsigned short)oi;
    }
}

// ---------------- scan kernel ----------------
// 512 blocks x 512 threads (8 waves). Block = one tile of 64 Morton-adjacent
// queries. Wave w scans candidates j = t*8+w (interleaved); partial top-16s
// merged via tree (8->4->2->1). Keys pack ORIGINAL index; d2 formula is the
// reference-exact one -> selected sets bit-identical to R4.
#define KIDX(s, w, l) (((s) * 8 + (w)) * 64 + (l))

__global__ __launch_bounds__(512) void scan_kernel(
    const float* __restrict__ pred, const float* __restrict__ gt,
    const float4* __restrict__ mort4, const unsigned short* __restrict__ midx,
    float* __restrict__ nP, float* __restrict__ nG, double* __restrict__ acc)
{
    __shared__ float4 sHome[NP];            // morton-ordered home (x,y,z,|p|^2)  32 KB
    __shared__ float4 sOther[NP];           // morton-ordered other              32 KB
    __shared__ unsigned short sOrig[NP];    // home morton-pos -> original idx    4 KB
    __shared__ float mbuf[8 * 64];          // per-wave chamfer partial mins      2 KB
    unsigned* kbuf = (unsigned*)sOther;     // reused post-scan: [16][8][64] u32 = 32 KB
    float* cache = (float*)sOther;          // reused in tail: gathered nbr pts

    int bi = blockIdx.x;
    bool predHome = bi < NB * 32;
    int lb = predHome ? bi : bi - NB * 32;
    int b = lb >> 5;
    int tile = lb & 31;
    int tid  = threadIdx.x;
    int wave = tid >> 6;
    int lane = tid & 63;
    int homeSel = predHome ? 0 : 1;

    const float* home = (predHome ? pred : gt) + (size_t)b * NP * 3;
    const float4* mh = mort4 + (size_t)(homeSel * NB + b) * NP;
    const float4* mo = mort4 + (size_t)((1 - homeSel) * NB + b) * NP;
    const unsigned short* mi = midx + (size_t)(homeSel * NB + b) * NP;

    for (int t = tid; t < NP; t += 512) {
        sHome[t]  = mh[t];
        sOther[t] = mo[t];
        sOrig[t]  = mi[t];
    }
    __syncthreads();

    int im = tile * 64 + lane;              // morton position of this query
    float4 q = sHome[im];
    float qx = q.x, qy = q.y, qz = q.z, qq = q.w;
    unsigned qoi = sOrig[im];               // original index (for normal output)

    unsigned keys[KN];
    #pragma unroll
    for (int s = 0; s < KN; ++s) keys[s] = 0x7F800000u | (unsigned)s;
    unsigned kmax = 0x7F800000u | 15u;

    auto insertKey = [&](unsigned key) {
        if (key < kmax) {
            #pragma unroll
            for (int s = 0; s < KN; ++s) keys[s] = (keys[s] == kmax) ? key : keys[s];
            unsigned m = keys[0];
            #pragma unroll
            for (int s = 1; s < KN; ++s) m = keys[s] > m ? keys[s] : m;
            kmax = m;
        }
    };

    float minv = 1e30f;

    for (int t = 0; t < NP / 8; ++t) {
        int jj = (t << 3) | wave;
        float4 h = sHome[jj];                                   // broadcast b128
        float dotj = dot_rn(qx, qy, qz, h.x, h.y, h.z);
        float d2 = __fsub_rn(__fadd_rn(qq, h.w), __fmul_rn(2.f, dotj));
        unsigned oi = sOrig[jj];                                // broadcast u16
        insertKey((__float_as_uint(d2) & 0xFFFFF800u) | oi);
        float4 o = sOther[jj];                                  // broadcast b128
        float ex = qx - o.x, ey = qy - o.y, ez = qz - o.z;
        minv = fminf(minv, fmaf(ex, ex, fmaf(ey, ey, ez * ez)));
    }
    __syncthreads();   // all sOther reads done before kbuf aliasing writes

    // publish partials (conflict-free transposed layout)
    #pragma unroll
    for (int s = 0; s < KN; ++s) kbuf[KIDX(s, wave, lane)] = keys[s];
    mbuf[wave * 64 + lane] = minv;
    __syncthreads();

    // tree merge: 8 -> 4 -> 2 -> 1 (sets disjoint-by-key; order-invariant)
    if (wave < 4) {
        #pragma unroll
        for (int s = 0; s < KN; ++s) insertKey(kbuf[KIDX(s, wave + 4, lane)]);
        minv = fminf(minv, mbuf[(wave + 4) * 64 + lane]);
        #pragma unroll
        for (int s = 0; s < KN; ++s) kbuf[KIDX(s, wave, lane)] = keys[s];
        mbuf[wave * 64 + lane] = minv;
    }
    __syncthreads();
    if (wave < 2) {
        #pragma unroll
        for (int s = 0; s < KN; ++s) insertKey(kbuf[KIDX(s, wave + 2, lane)]);
        minv = fminf(minv, mbuf[(wave + 2) * 64 + lane]);
        #pragma unroll
        for (int s = 0; s < KN; ++s) kbuf[KIDX(s, wave, lane)] = keys[s];
        mbuf[wave * 64 + lane] = minv;
    }
    __syncthreads();
    if (wave != 0) return;

    #pragma unroll
    for (int s = 0; s < KN; ++s) insertKey(kbuf[KIDX(s, 1, lane)]);
    minv = fminf(minv, mbuf[64 + lane]);

    // --- gather neighbors by ORIGINAL index from global (L2-hot), cache in LDS ---
    float sx = 0.f, sy = 0.f, sz = 0.f;
    #pragma unroll
    for (int s = 0; s < KN; ++s) {
        const float* hp = home + 3 * (size_t)(keys[s] & 0x7FFu);
        float px = hp[0], py = hp[1], pz = hp[2];
        cache[(s * 3 + 0) * 64 + lane] = px;
        cache[(s * 3 + 1) * 64 + lane] = py;
        cache[(s * 3 + 2) * 64 + lane] = pz;
        sx += px; sy += py; sz += pz;
    }
    float mx = sx * (1.0f / KN), my = sy * (1.0f / KN), mz = sz * (1.0f / KN);
    float cxx = 0.f, cxy = 0.f, cxz = 0.f, cyy = 0.f, cyz = 0.f, czz = 0.f;
    #pragma unroll
    for (int s = 0; s < KN; ++s) {
        float ax = cache[(s * 3 + 0) * 64 + lane] - mx;
        float ay = cache[(s * 3 + 1) * 64 + lane] - my;
        float az = cache[(s * 3 + 2) * 64 + lane] - mz;
        cxx += ax * ax; cxy += ax * ay; cxz += ax * az;
        cyy += ay * ay; cyz += ay * az; czz += az * az;
    }
    cxx *= (1.f / KN); cxy *= (1.f / KN); cxz *= (1.f / KN);
    cyy *= (1.f / KN); cyz *= (1.f / KN); czz *= (1.f / KN);

    // --- repulsion: 4 nearest excluding self (pred side only); destroys keys ---
    float rep = 0.0f;
    if (predHome) {
        #pragma unroll
        for (int r = 0; r < 5; ++r) {
            unsigned m = keys[0];
            #pragma unroll
            for (int s = 1; s < KN; ++s) m = keys[s] < m ? keys[s] : m;
            if (r > 0) {
                float d2 = __uint_as_float(m & 0xFFFFF800u);
                float dd = sqrtf(fmaxf(d2, 1e-12f));
                rep += fmaxf(0.02f - dd, 0.0f);
            }
            #pragma unroll
            for (int s = 0; s < KN; ++s) keys[s] = (keys[s] == m) ? 0xFFFFFFFFu : keys[s];
        }
    }

    // --- normal via faithful ssyevd emulation ---
    float nx, ny, nz;
    ssyevd3_evec0(cxx, cxy, cxz, cyy, cyz, czz, &nx, &ny, &nz);

    float* nout = predHome ? nP : nG;
    int gi = b * NP + (int)qoi;
    nout[gi * 3 + 0] = nx;
    nout[gi * 3 + 1] = ny;
    nout[gi * 3 + 2] = nz;

    double part = (double)minv * (1.0 / (NB * NP))
                + (double)rep  * (0.1 / (NB * NP * 4));

    #pragma unroll
    for (int off = 32; off > 0; off >>= 1) part += __shfl_down(part, off);
    if (lane == 0) atomicAdd(acc, part);
}

// ---------------------------------------------------------------------------
__global__ __launch_bounds__(256) void dot_kernel(
    const float* __restrict__ nP, const float* __restrict__ nG, double* __restrict__ acc)
{
    int i = blockIdx.x * 256 + threadIdx.x;
    float d = nP[i * 3] * nG[i * 3] + nP[i * 3 + 1] * nG[i * 3 + 1] + nP[i * 3 + 2] * nG[i * 3 + 2];
    double part = (double)d * (-0.01 / (NB * NP));
    #pragma unroll
    for (int off = 32; off > 0; off >>= 1) part += __shfl_down(part, off);
    if ((threadIdx.x & 63) == 0) atomicAdd(acc, part);
}

__global__ void fin_kernel(const double* __restrict__ acc, float* __restrict__ out)
{
    out[0] = (float)(acc[0] + 0.01);
}

// ---------------------------------------------------------------------------
extern "C" void kernel_launch(void* const* d_in, const int* in_sizes, int n_in,
                              void* d_out, int out_size, void* d_ws, size_t ws_size,
                              hipStream_t stream)
{
    const float* pred = (const float*)d_in[0];
    const float* gt   = (const float*)d_in[1];

    // ws layout: acc(64) | mort4 (2*8*2048*16 = 524288) | midx (2*8*2048*2 = 65536) | nP | nG
    char* base = (char*)d_ws;
    double* acc = (double*)base;
    float4* mort4 = (float4*)(base + 64);
    unsigned short* midx = (unsigned short*)(base + 64 + 524288);
    float* nP = (float*)(base + 64 + 524288 + 65536);
    float* nG = nP + (size_t)NB * NP * 3;

    hipMemsetAsync(d_ws, 0, 64, stream);
    sort_kernel<<<dim3(16), dim3(1024), 0, stream>>>(pred, gt, mort4, midx);
    scan_kernel<<<dim3(NB * 32 * 2), dim3(512), 0, stream>>>(pred, gt, mort4, midx, nP, nG, acc);
    dot_kernel<<<dim3(NB * NP / 256), dim3(256), 0, stream>>>(nP, nG, acc);
    fin_kernel<<<dim3(1), dim3(1), 0, stream>>>(acc, (float*)d_out);
}

// Round 6
// 216.636 us; speedup vs baseline: 2.5661x; 1.0080x over previous
//
#include <hip/hip_runtime.h>

// CombinedLoss: chamfer(pred,gt) + 0.1*repulsion(pred,k=4) + 0.01*(1 - mean(n_pred . n_gt))
// B=8, N=2048, fp32 in, fp32 scalar out.
// Normals match np.linalg.eigh (LAPACK ssyevd) signs point-by-point via faithful
// fp32 ssytd2+ssteqr+sormtr emulation (R3-R5: absmax 0.0).
// R6: wave-uniform insert skip (__any + s_cbranch; R5 post-mortem showed the
// per-lane branch was if-converted -> 91 inst/iter) + circular Morton scan
// starting at the query tile (kmax converges in first ~30 iters -> trigger-rate
// collapses). Key construction/d2 formula untouched -> selection bit-identical.

#define NB 8
#define NP 2048
#define KN 16

// ---------------- LAPACK helpers (fp32, faithful — DO NOT TOUCH) ----------------

__device__ __forceinline__ float f_slapy2(float x, float y) {
    float xa = fabsf(x), ya = fabsf(y);
    float w = fmaxf(xa, ya), zm = fminf(xa, ya);
    if (zm == 0.f) return w;
    float q = zm / w;
    return w * sqrtf(1.f + q * q);
}

// LAPACK >=3.10 slartg convention: c >= 0 always.
__device__ __forceinline__ void f_slartg(float f, float g, float* cs, float* sn, float* r) {
    if (g == 0.f) { *cs = 1.f; *sn = 0.f; *r = f; }
    else if (f == 0.f) { *cs = 0.f; *sn = copysignf(1.f, g); *r = fabsf(g); }
    else {
        float d = sqrtf(__fadd_rn(__fmul_rn(f, f), __fmul_rn(g, g)));
        *cs = fabsf(f) / d;
        *r  = copysignf(d, f);
        *sn = g / *r;
    }
}

__device__ void f_slaev2(float a, float b, float c,
                         float* rt1, float* rt2, float* cs1, float* sn1) {
    float sm = a + c;
    float df = a - c;
    float adf = fabsf(df);
    float tb = b + b;
    float ab = fabsf(tb);
    float acmx, acmn;
    if (fabsf(a) > fabsf(c)) { acmx = a; acmn = c; } else { acmx = c; acmn = a; }
    float rt;
    if (adf > ab)      { float q = ab / adf; rt = adf * sqrtf(1.f + q * q); }
    else if (adf < ab) { float q = adf / ab; rt = ab * sqrtf(1.f + q * q); }
    else               rt = ab * sqrtf(2.f);
    int sgn1;
    if (sm < 0.f) {
        *rt1 = 0.5f * (sm - rt); sgn1 = -1;
        *rt2 = (acmx / *rt1) * acmn - (b / *rt1) * b;
    } else if (sm > 0.f) {
        *rt1 = 0.5f * (sm + rt); sgn1 = 1;
        *rt2 = (acmx / *rt1) * acmn - (b / *rt1) * b;
    } else {
        *rt1 = 0.5f * rt; *rt2 = -0.5f * rt; sgn1 = 1;
    }
    float cs; int sgn2;
    if (df >= 0.f) { cs = df + rt; sgn2 = 1; }
    else           { cs = df - rt; sgn2 = -1; }
    float acs = fabsf(cs);
    if (acs > ab) {
        float ct = -tb / cs;
        *sn1 = 1.f / sqrtf(1.f + ct * ct);
        *cs1 = ct * *sn1;
    } else {
        if (ab == 0.f) { *cs1 = 1.f; *sn1 = 0.f; }
        else {
            float tn = -cs / tb;
            *cs1 = 1.f / sqrtf(1.f + tn * tn);
            *sn1 = tn * *cs1;
        }
    }
    if (sgn1 == sgn2) { float tn = *cs1; *cs1 = -*sn1; *sn1 = tn; }
}

// fp32 ssyevd for a 3x3 symmetric matrix (lower triangle given), returns
// eigenvector of the SMALLEST eigenvalue, with LAPACK's sign convention.
__device__ void ssyevd3_evec0(float a00, float a10, float a20,
                              float a11, float a21, float a22,
                              float* ox, float* oy, float* oz) {
    // ---- ssytd2('L') ----
    float d[3], e[2];
    float tau = 0.f, v2 = 0.f;
    float xnorm = fabsf(a20);
    if (xnorm == 0.f) {
        tau = 0.f;
        d[0] = a00; d[1] = a11; d[2] = a22; e[0] = a10; e[1] = a21;
    } else {
        float beta = -copysignf(f_slapy2(a10, xnorm), a10);
        tau = (beta - a10) / beta;
        float inv = 1.f / (a10 - beta);
        v2 = a20 * inv;
        float x1 = tau * (a11 + a21 * v2);
        float x2 = tau * (a21 + a22 * v2);
        float alpha = -0.5f * tau * (x1 + x2 * v2);
        float w1 = x1 + alpha;
        float w2 = x2 + alpha * v2;
        float b11 = a11 - 2.f * w1;
        float b21 = a21 - v2 * w1 - w2;
        float b22 = a22 - 2.f * (v2 * w2);
        d[0] = a00; d[1] = b11; d[2] = b22; e[0] = beta; e[1] = b21;
    }
    // ---- ssteqr('I', n=3) ----
    const float eps    = 5.9604645e-08f;
    const float eps2   = eps * eps;
    const float safmin = 1.1754944e-38f;
    const float ssfmax = sqrtf(1.f / safmin) / 3.f;
    const float ssfmin = sqrtf(safmin) / eps2;
    const int n = 3, nmaxit = 90;
    float z[3][3] = {{1.f,0.f,0.f},{0.f,1.f,0.f},{0.f,0.f,1.f}};
    int jtot = 0;
    int l1 = 1;

    while (true) {
        if (l1 > n) break;
        if (l1 > 1) e[l1 - 2] = 0.f;
        int m = n;
        for (int mi = l1; mi <= n - 1; ++mi) {
            float tst = fabsf(e[mi - 1]);
            if (tst == 0.f) { m = mi; break; }
            if (tst <= (sqrtf(fabsf(d[mi - 1])) * sqrtf(fabsf(d[mi]))) * eps) {
                e[mi - 1] = 0.f; m = mi; break;
            }
        }
        int l = l1, lsv = l, lend = m, lendsv = lend;
        l1 = m + 1;
        if (lend == l) continue;

        float anorm = 0.f;
        for (int i = l; i <= lend; ++i) anorm = fmaxf(anorm, fabsf(d[i - 1]));
        for (int i = l; i <= lend - 1; ++i) anorm = fmaxf(anorm, fabsf(e[i - 1]));
        int iscale = 0; float sclto = 1.f;
        if (anorm == 0.f) continue;
        if (anorm > ssfmax) { iscale = 1; sclto = ssfmax; }
        else if (anorm < ssfmin) { iscale = 2; sclto = ssfmin; }
        if (iscale) {
            float mul = sclto / anorm;
            for (int i = l; i <= lend; ++i) d[i - 1] *= mul;
            for (int i = l; i <= lend - 1; ++i) e[i - 1] *= mul;
        }
        if (fabsf(d[lend - 1]) < fabsf(d[l - 1])) { lend = lsv; l = lendsv; }

        if (lend > l) {
            // QL
            while (true) {
                int mq = lend;
                if (l != lend) {
                    for (int i = l; i <= lend - 1; ++i) {
                        float ei = e[i - 1];
                        float tst = ei * ei;
                        if (tst <= (eps2 * fabsf(d[i - 1])) * fabsf(d[i]) + safmin) { mq = i; break; }
                    }
                }
                if (mq < lend) e[mq - 1] = 0.f;
                float p = d[l - 1];
                if (mq == l) { d[l - 1] = p; l = l + 1; if (l <= lend) continue; break; }
                if (mq == l + 1) {
                    float rt1, rt2, c, s;
                    f_slaev2(d[l - 1], e[l - 1], d[l], &rt1, &rt2, &c, &s);
                    for (int i = 0; i < 3; ++i) {
                        float temp = z[i][l];
                        z[i][l]     = c * temp - s * z[i][l - 1];
                        z[i][l - 1] = s * temp + c * z[i][l - 1];
                    }
                    d[l - 1] = rt1; d[l] = rt2; e[l - 1] = 0.f;
                    l += 2; if (l <= lend) continue; break;
                }
                if (jtot == nmaxit) break;
                jtot++;
                float g = (d[l] - p) / (2.f * e[l - 1]);
                float r = f_slapy2(g, 1.f);
                g = d[mq - 1] - p + e[l - 1] / (g + copysignf(r, g));
                float s = 1.f, c = 1.f; p = 0.f;
                float cw[2], sw[2];
                for (int i = mq - 1; i >= l; --i) {
                    float f = s * e[i - 1];
                    float b = c * e[i - 1];
                    f_slartg(g, f, &c, &s, &r);
                    if (i != mq - 1) e[i] = r;
                    g = d[i] - p;
                    r = (d[i - 1] - g) * s + 2.f * c * b;
                    p = s * r;
                    d[i] = g + p;
                    g = c * r - b;
                    cw[i - l] = c; sw[i - l] = -s;
                }
                for (int j = mq - l; j >= 1; --j) {
                    float cj = cw[j - 1], sj = sw[j - 1];
                    int c0 = l - 1 + (j - 1);
                    for (int i = 0; i < 3; ++i) {
                        float temp = z[i][c0 + 1];
                        z[i][c0 + 1] = cj * temp - sj * z[i][c0];
                        z[i][c0]     = sj * temp + cj * z[i][c0];
                    }
                }
                d[l - 1] -= p;
                e[l - 1] = g;
            }
        } else {
            // QR
            while (true) {
                int mq = lend;
                if (l != lend) {
                    for (int i = l; i >= lend + 1; --i) {
                        float ei = e[i - 2];
                        float tst = ei * ei;
                        if (tst <= (eps2 * fabsf(d[i - 1])) * fabsf(d[i - 2]) + safmin) { mq = i; break; }
                    }
                }
                if (mq > lend) e[mq - 2] = 0.f;
                float p = d[l - 1];
                if (mq == l) { d[l - 1] = p; l = l - 1; if (l >= lend) continue; break; }
                if (mq == l - 1) {
                    float rt1, rt2, c, s;
                    f_slaev2(d[l - 2], e[l - 2], d[l - 1], &rt1, &rt2, &c, &s);
                    for (int i = 0; i < 3; ++i) {
                        float temp = z[i][l - 1];
                        z[i][l - 1] = c * temp - s * z[i][l - 2];
                        z[i][l - 2] = s * temp + c * z[i][l - 2];
                    }
                    d[l - 2] = rt1; d[l - 1] = rt2; e[l - 2] = 0.f;
                    l -= 2; if (l >= lend) continue; break;
                }
                if (jtot == nmaxit) break;
                jtot++;
                float g = (d[l - 2] - p) / (2.f * e[l - 2]);
                float r = f_slapy2(g, 1.f);
                g = d[mq - 1] - p + e[l - 2] / (g + copysignf(r, g));
                float s = 1.f, c = 1.f; p = 0.f;
                float cw[2], sw[2];
                for (int i = mq; i <= l - 1; ++i) {
                    float f = s * e[i - 1];
                    float b = c * e[i - 1];
                    f_slartg(g, f, &c, &s, &r);
                    if (i != mq) e[i - 2] = r;
                    g = d[i - 1] - p;
                    r = (d[i] - g) * s + 2.f * c * b;
                    p = s * r;
                    d[i - 1] = g + p;
                    g = c * r - b;
                    cw[i - mq] = c; sw[i - mq] = s;
                }
                for (int j = 1; j <= l - mq; ++j) {
                    float cj = cw[j - 1], sj = sw[j - 1];
                    int c0 = mq - 1 + (j - 1);
                    for (int i = 0; i < 3; ++i) {
                        float temp = z[i][c0 + 1];
                        z[i][c0 + 1] = cj * temp - sj * z[i][c0];
                        z[i][c0]     = sj * temp + cj * z[i][c0];
                    }
                }
                d[l - 1] -= p;
                e[l - 2] = g;
            }
        }
        if (iscale) {
            float mul = anorm / sclto;
            for (int i = lsv; i <= lendsv; ++i) d[i - 1] *= mul;
            for (int i = lsv; i <= lendsv - 1; ++i) e[i - 1] *= mul;
        }
        if (jtot >= nmaxit) break;
    }

    // sort ascending (column swaps — no sign change)
    for (int ii = 2; ii <= 3; ++ii) {
        int i = ii - 1, k = i;
        float p = d[i - 1];
        for (int j = ii; j <= 3; ++j) if (d[j - 1] < p) { k = j; p = d[j - 1]; }
        if (k != i) {
            d[k - 1] = d[i - 1]; d[i - 1] = p;
            for (int r = 0; r < 3; ++r) { float t = z[r][i - 1]; z[r][i - 1] = z[r][k - 1]; z[r][k - 1] = t; }
        }
    }
    // sormtr('L','L','N')
    float r0 = z[0][0], r1 = z[1][0], r2 = z[2][0];
    if (tau != 0.f) {
        float sum = r1 + v2 * r2;
        r1 -= tau * sum;
        r2 -= tau * (v2 * sum);
    }
    *ox = r0; *oy = r1; *oz = r2;
}

// ---------------- common ----------------

__device__ __forceinline__ float dot_rn(float ax, float ay, float az,
                                        float bx, float by, float bz) {
    return __fadd_rn(__fadd_rn(__fmul_rn(ax, bx), __fmul_rn(ay, by)), __fmul_rn(az, bz));
}

__device__ __forceinline__ unsigned spread7(unsigned v) {
    v &= 0x7Fu;
    v = (v | (v << 16)) & 0x030000FFu;
    v = (v | (v << 8))  & 0x0300F00Fu;
    v = (v | (v << 4))  & 0x030C30C3u;
    v = (v | (v << 2))  & 0x09249249u;
    return v;
}

// ---------------- sort kernel ----------------
__global__ __launch_bounds__(1024) void sort_kernel(
    const float* __restrict__ pred, const float* __restrict__ gt,
    float4* __restrict__ mort4, unsigned short* __restrict__ midx)
{
    __shared__ unsigned sk[NP];
    int bc = blockIdx.x;
    int cloud = bc >> 3, b = bc & 7;
    const float* src = (cloud ? gt : pred) + (size_t)b * NP * 3;
    int tid = threadIdx.x;

    for (int t = tid; t < NP; t += 1024) {
        float x = src[3 * t], y = src[3 * t + 1], z = src[3 * t + 2];
        unsigned ix = (unsigned)fminf(fmaxf(x, 0.f) * 128.f, 127.f);
        unsigned iy = (unsigned)fminf(fmaxf(y, 0.f) * 128.f, 127.f);
        unsigned iz = (unsigned)fminf(fmaxf(z, 0.f) * 128.f, 127.f);
        unsigned morton = (spread7(ix) << 2) | (spread7(iy) << 1) | spread7(iz);
        sk[t] = (morton << 11) | (unsigned)t;
    }
    __syncthreads();
    for (unsigned k = 2; k <= NP; k <<= 1) {
        for (unsigned j = k >> 1; j > 0; j >>= 1) {
            for (int t = tid; t < NP; t += 1024) {
                unsigned ixj = (unsigned)t ^ j;
                if (ixj > (unsigned)t) {
                    unsigned a = sk[t], c = sk[ixj];
                    bool up = (((unsigned)t & k) == 0);
                    if ((a > c) == up) { sk[t] = c; sk[ixj] = a; }
                }
            }
            __syncthreads();
        }
    }
    float4* out4 = mort4 + (size_t)bc * NP;
    unsigned short* oix = midx + (size_t)bc * NP;
    for (int t = tid; t < NP; t += 1024) {
        unsigned oi = sk[t] & 0x7FFu;
        float x = src[3 * oi], y = src[3 * oi + 1], z = src[3 * oi + 2];
        out4[t] = make_float4(x, y, z, dot_rn(x, y, z, x, y, z));
        oix[t] = (unsigned short)oi;
    }
}

// ---------------- scan kernel ----------------
// 512 blocks x 512 threads (8 waves). Block = tile of 64 Morton-adjacent
// queries. Wave w scans candidates jj = (tileStart + 8t + w) mod 2048 —
// CIRCULAR from the tile, so near candidates come first and kmax converges
// within ~30 iters. Insert guarded by __any (wave-uniform s_cbranch).
// Keys pack ORIGINAL index; d2 is reference-exact -> selection bit-identical.
#define KIDX(s, w, l) (((s) * 8 + (w)) * 64 + (l))

__global__ __launch_bounds__(512) void scan_kernel(
    const float* __restrict__ pred, const float* __restrict__ gt,
    const float4* __restrict__ mort4, const unsigned short* __restrict__ midx,
    float* __restrict__ nP, float* __restrict__ nG, double* __restrict__ acc)
{
    __shared__ float4 sHome[NP];            // morton-ordered home (x,y,z,|p|^2)  32 KB
    __shared__ float4 sOther[NP];           // morton-ordered other              32 KB
    __shared__ unsigned short sOrig[NP];    // home morton-pos -> original idx    4 KB
    __shared__ float mbuf[8 * 64];          // per-wave chamfer partial mins      2 KB
    unsigned* kbuf = (unsigned*)sOther;     // reused post-scan: [16][8][64] u32
    float* cache = (float*)sOther;          // reused in tail: gathered nbr pts

    int bi = blockIdx.x;
    bool predHome = bi < NB * 32;
    int lb = predHome ? bi : bi - NB * 32;
    int b = lb >> 5;
    int tile = lb & 31;
    int tid  = threadIdx.x;
    int wave = tid >> 6;
    int lane = tid & 63;
    int homeSel = predHome ? 0 : 1;

    const float* home = (predHome ? pred : gt) + (size_t)b * NP * 3;
    const float4* mh = mort4 + (size_t)(homeSel * NB + b) * NP;
    const float4* mo = mort4 + (size_t)((1 - homeSel) * NB + b) * NP;
    const unsigned short* mi = midx + (size_t)(homeSel * NB + b) * NP;

    for (int t = tid; t < NP; t += 512) {
        sHome[t]  = mh[t];
        sOther[t] = mo[t];
        sOrig[t]  = mi[t];
    }
    __syncthreads();

    int im = tile * 64 + lane;              // morton position of this query
    float4 q = sHome[im];
    float qx = q.x, qy = q.y, qz = q.z, qq = q.w;
    unsigned qoi = sOrig[im];               // original index (for normal output)

    unsigned keys[KN];
    #pragma unroll
    for (int s = 0; s < KN; ++s) keys[s] = 0x7F800000u | (unsigned)s;
    unsigned kmax = 0x7F800000u | 15u;

    auto insertKey = [&](unsigned key) {
        if (__any(key < kmax)) {            // wave-uniform scalar branch
            if (key < kmax) {               // per-lane predication inside
                #pragma unroll
                for (int s = 0; s < KN; ++s) keys[s] = (keys[s] == kmax) ? key : keys[s];
                unsigned m = keys[0];
                #pragma unroll
                for (int s = 1; s < KN; ++s) m = keys[s] > m ? keys[s] : m;
                kmax = m;
            }
        }
    };

    float minv = 1e30f;
    int tileStart = tile * 64;

    for (int t = 0; t < NP / 8; ++t) {
        int jj = (tileStart + ((t << 3) | wave)) & (NP - 1);   // circular from tile
        float4 h = sHome[jj];                                  // broadcast b128
        float dotj = dot_rn(qx, qy, qz, h.x, h.y, h.z);
        float d2 = __fsub_rn(__fadd_rn(qq, h.w), __fmul_rn(2.f, dotj));
        unsigned oi = sOrig[jj];                               // broadcast u16
        insertKey((__float_as_uint(d2) & 0xFFFFF800u) | oi);
        float4 o = sOther[jj];                                 // broadcast b128
        float ex = qx - o.x, ey = qy - o.y, ez = qz - o.z;
        minv = fminf(minv, fmaf(ex, ex, fmaf(ey, ey, ez * ez)));
    }
    __syncthreads();   // all sOther reads done before kbuf aliasing writes

    // publish partials (conflict-free transposed layout)
    #pragma unroll
    for (int s = 0; s < KN; ++s) kbuf[KIDX(s, wave, lane)] = keys[s];
    mbuf[wave * 64 + lane] = minv;
    __syncthreads();

    // tree merge: 8 -> 4 -> 2 -> 1 (distinct keys; order-invariant set)
    if (wave < 4) {
        #pragma unroll
        for (int s = 0; s < KN; ++s) insertKey(kbuf[KIDX(s, wave + 4, lane)]);
        minv = fminf(minv, mbuf[(wave + 4) * 64 + lane]);
        #pragma unroll
        for (int s = 0; s < KN; ++s) kbuf[KIDX(s, wave, lane)] = keys[s];
        mbuf[wave * 64 + lane] = minv;
    }
    __syncthreads();
    if (wave < 2) {
        #pragma unroll
        for (int s = 0; s < KN; ++s) insertKey(kbuf[KIDX(s, wave + 2, lane)]);
        minv = fminf(minv, mbuf[(wave + 2) * 64 + lane]);
        #pragma unroll
        for (int s = 0; s < KN; ++s) kbuf[KIDX(s, wave, lane)] = keys[s];
        mbuf[wave * 64 + lane] = minv;
    }
    __syncthreads();
    if (wave != 0) return;

    #pragma unroll
    for (int s = 0; s < KN; ++s) insertKey(kbuf[KIDX(s, 1, lane)]);
    minv = fminf(minv, mbuf[64 + lane]);

    // --- gather neighbors by ORIGINAL index from global (L2-hot), cache in LDS ---
    float sx = 0.f, sy = 0.f, sz = 0.f;
    #pragma unroll
    for (int s = 0; s < KN; ++s) {
        const float* hp = home + 3 * (size_t)(keys[s] & 0x7FFu);
        float px = hp[0], py = hp[1], pz = hp[2];
        cache[(s * 3 + 0) * 64 + lane] = px;
        cache[(s * 3 + 1) * 64 + lane] = py;
        cache[(s * 3 + 2) * 64 + lane] = pz;
        sx += px; sy += py; sz += pz;
    }
    float mx = sx * (1.0f / KN), my = sy * (1.0f / KN), mz = sz * (1.0f / KN);
    float cxx = 0.f, cxy = 0.f, cxz = 0.f, cyy = 0.f, cyz = 0.f, czz = 0.f;
    #pragma unroll
    for (int s = 0; s < KN; ++s) {
        float ax = cache[(s * 3 + 0) * 64 + lane] - mx;
        float ay = cache[(s * 3 + 1) * 64 + lane] - my;
        float az = cache[(s * 3 + 2) * 64 + lane] - mz;
        cxx += ax * ax; cxy += ax * ay; cxz += ax * az;
        cyy += ay * ay; cyz += ay * az; czz += az * az;
    }
    cxx *= (1.f / KN); cxy *= (1.f / KN); cxz *= (1.f / KN);
    cyy *= (1.f / KN); cyz *= (1.f / KN); czz *= (1.f / KN);

    // --- repulsion: 4 nearest excluding self (pred side only); destroys keys ---
    float rep = 0.0f;
    if (predHome) {
        #pragma unroll
        for (int r = 0; r < 5; ++r) {
            unsigned m = keys[0];
            #pragma unroll
            for (int s = 1; s < KN; ++s) m = keys[s] < m ? keys[s] : m;
            if (r > 0) {
                float d2 = __uint_as_float(m & 0xFFFFF800u);
                float dd = sqrtf(fmaxf(d2, 1e-12f));
                rep += fmaxf(0.02f - dd, 0.0f);
            }
            #pragma unroll
            for (int s = 0; s < KN; ++s) keys[s] = (keys[s] == m) ? 0xFFFFFFFFu : keys[s];
        }
    }

    // --- normal via faithful ssyevd emulation ---
    float nx, ny, nz;
    ssyevd3_evec0(cxx, cxy, cxz, cyy, cyz, czz, &nx, &ny, &nz);

    float* nout = predHome ? nP : nG;
    int gi = b * NP + (int)qoi;
    nout[gi * 3 + 0] = nx;
    nout[gi * 3 + 1] = ny;
    nout[gi * 3 + 2] = nz;

    double part = (double)minv * (1.0 / (NB * NP))
                + (double)rep  * (0.1 / (NB * NP * 4));

    #pragma unroll
    for (int off = 32; off > 0; off >>= 1) part += __shfl_down(part, off);
    if (lane == 0) atomicAdd(acc, part);
}

// ---------------------------------------------------------------------------
// Fused normal-dot + finalize: single block, runs after scan (stream order).
__global__ __launch_bounds__(1024) void dotfin_kernel(
    const float* __restrict__ nP, const float* __restrict__ nG,
    const double* __restrict__ acc, float* __restrict__ out)
{
    int tid = threadIdx.x;
    float s = 0.f;
    for (int i = tid; i < NB * NP; i += 1024)
        s += nP[3 * i] * nG[3 * i] + nP[3 * i + 1] * nG[3 * i + 1] + nP[3 * i + 2] * nG[3 * i + 2];
    double part = (double)s;
    #pragma unroll
    for (int off = 32; off > 0; off >>= 1) part += __shfl_down(part, off);
    __shared__ double w[16];
    if ((tid & 63) == 0) w[tid >> 6] = part;
    __syncthreads();
    if (tid == 0) {
        double t = 0.0;
        for (int k = 0; k < 16; ++k) t += w[k];
        out[0] = (float)(acc[0] - t * (0.01 / (NB * NP)) + 0.01);
    }
}

// ---------------------------------------------------------------------------
extern "C" void kernel_launch(void* const* d_in, const int* in_sizes, int n_in,
                              void* d_out, int out_size, void* d_ws, size_t ws_size,
                              hipStream_t stream)
{
    const float* pred = (const float*)d_in[0];
    const float* gt   = (const float*)d_in[1];

    // ws layout: acc(64) | mort4 (524288) | midx (65536) | nP | nG
    char* base = (char*)d_ws;
    double* acc = (double*)base;
    float4* mort4 = (float4*)(base + 64);
    unsigned short* midx = (unsigned short*)(base + 64 + 524288);
    float* nP = (float*)(base + 64 + 524288 + 65536);
    float* nG = nP + (size_t)NB * NP * 3;

    hipMemsetAsync(d_ws, 0, 64, stream);
    sort_kernel<<<dim3(16), dim3(1024), 0, stream>>>(pred, gt, mort4, midx);
    scan_kernel<<<dim3(NB * 32 * 2), dim3(512), 0, stream>>>(pred, gt, mort4, midx, nP, nG, acc);
    dotfin_kernel<<<dim3(1), dim3(1024), 0, stream>>>(nP, nG, acc, (float*)d_out);
}

// Round 7
// 203.750 us; speedup vs baseline: 2.7284x; 1.0632x over previous
//
#include <hip/hip_runtime.h>

// CombinedLoss: chamfer(pred,gt) + 0.1*repulsion(pred,k=4) + 0.01*(1 - mean(n_pred . n_gt))
// B=8, N=2048, fp32 in, fp32 scalar out.
// Normals match np.linalg.eigh (LAPACK ssyevd) signs point-by-point via faithful
// fp32 ssytd2+ssteqr+sormtr emulation (R3-R6: absmax 0.0).
// R7: (1) seed each wave's top-16 heap with 16 real candidates from its own
// slice near the tile (skipped in main loop; disjoint across waves -> exact),
// giving a tight initial kmax so the __any insert branch actually skips;
// (2) LDS 70K->60K so 2 blocks/CU co-reside; (3) padded bitonic sort indices.

#define NB 8
#define NP 2048
#define KN 16

// ---------------- LAPACK helpers (fp32, faithful — DO NOT TOUCH) ----------------

__device__ __forceinline__ float f_slapy2(float x, float y) {
    float xa = fabsf(x), ya = fabsf(y);
    float w = fmaxf(xa, ya), zm = fminf(xa, ya);
    if (zm == 0.f) return w;
    float q = zm / w;
    return w * sqrtf(1.f + q * q);
}

// LAPACK >=3.10 slartg convention: c >= 0 always.
__device__ __forceinline__ void f_slartg(float f, float g, float* cs, float* sn, float* r) {
    if (g == 0.f) { *cs = 1.f; *sn = 0.f; *r = f; }
    else if (f == 0.f) { *cs = 0.f; *sn = copysignf(1.f, g); *r = fabsf(g); }
    else {
        float d = sqrtf(__fadd_rn(__fmul_rn(f, f), __fmul_rn(g, g)));
        *cs = fabsf(f) / d;
        *r  = copysignf(d, f);
        *sn = g / *r;
    }
}

__device__ void f_slaev2(float a, float b, float c,
                         float* rt1, float* rt2, float* cs1, float* sn1) {
    float sm = a + c;
    float df = a - c;
    float adf = fabsf(df);
    float tb = b + b;
    float ab = fabsf(tb);
    float acmx, acmn;
    if (fabsf(a) > fabsf(c)) { acmx = a; acmn = c; } else { acmx = c; acmn = a; }
    float rt;
    if (adf > ab)      { float q = ab / adf; rt = adf * sqrtf(1.f + q * q); }
    else if (adf < ab) { float q = adf / ab; rt = ab * sqrtf(1.f + q * q); }
    else               rt = ab * sqrtf(2.f);
    int sgn1;
    if (sm < 0.f) {
        *rt1 = 0.5f * (sm - rt); sgn1 = -1;
        *rt2 = (acmx / *rt1) * acmn - (b / *rt1) * b;
    } else if (sm > 0.f) {
        *rt1 = 0.5f * (sm + rt); sgn1 = 1;
        *rt2 = (acmx / *rt1) * acmn - (b / *rt1) * b;
    } else {
        *rt1 = 0.5f * rt; *rt2 = -0.5f * rt; sgn1 = 1;
    }
    float cs; int sgn2;
    if (df >= 0.f) { cs = df + rt; sgn2 = 1; }
    else           { cs = df - rt; sgn2 = -1; }
    float acs = fabsf(cs);
    if (acs > ab) {
        float ct = -tb / cs;
        *sn1 = 1.f / sqrtf(1.f + ct * ct);
        *cs1 = ct * *sn1;
    } else {
        if (ab == 0.f) { *cs1 = 1.f; *sn1 = 0.f; }
        else {
            float tn = -cs / tb;
            *cs1 = 1.f / sqrtf(1.f + tn * tn);
            *sn1 = tn * *cs1;
        }
    }
    if (sgn1 == sgn2) { float tn = *cs1; *cs1 = -*sn1; *sn1 = tn; }
}

// fp32 ssyevd for a 3x3 symmetric matrix (lower triangle given), returns
// eigenvector of the SMALLEST eigenvalue, with LAPACK's sign convention.
__device__ void ssyevd3_evec0(float a00, float a10, float a20,
                              float a11, float a21, float a22,
                              float* ox, float* oy, float* oz) {
    // ---- ssytd2('L') ----
    float d[3], e[2];
    float tau = 0.f, v2 = 0.f;
    float xnorm = fabsf(a20);
    if (xnorm == 0.f) {
        tau = 0.f;
        d[0] = a00; d[1] = a11; d[2] = a22; e[0] = a10; e[1] = a21;
    } else {
        float beta = -copysignf(f_slapy2(a10, xnorm), a10);
        tau = (beta - a10) / beta;
        float inv = 1.f / (a10 - beta);
        v2 = a20 * inv;
        float x1 = tau * (a11 + a21 * v2);
        float x2 = tau * (a21 + a22 * v2);
        float alpha = -0.5f * tau * (x1 + x2 * v2);
        float w1 = x1 + alpha;
        float w2 = x2 + alpha * v2;
        float b11 = a11 - 2.f * w1;
        float b21 = a21 - v2 * w1 - w2;
        float b22 = a22 - 2.f * (v2 * w2);
        d[0] = a00; d[1] = b11; d[2] = b22; e[0] = beta; e[1] = b21;
    }
    // ---- ssteqr('I', n=3) ----
    const float eps    = 5.9604645e-08f;
    const float eps2   = eps * eps;
    const float safmin = 1.1754944e-38f;
    const float ssfmax = sqrtf(1.f / safmin) / 3.f;
    const float ssfmin = sqrtf(safmin) / eps2;
    const int n = 3, nmaxit = 90;
    float z[3][3] = {{1.f,0.f,0.f},{0.f,1.f,0.f},{0.f,0.f,1.f}};
    int jtot = 0;
    int l1 = 1;

    while (true) {
        if (l1 > n) break;
        if (l1 > 1) e[l1 - 2] = 0.f;
        int m = n;
        for (int mi = l1; mi <= n - 1; ++mi) {
            float tst = fabsf(e[mi - 1]);
            if (tst == 0.f) { m = mi; break; }
            if (tst <= (sqrtf(fabsf(d[mi - 1])) * sqrtf(fabsf(d[mi]))) * eps) {
                e[mi - 1] = 0.f; m = mi; break;
            }
        }
        int l = l1, lsv = l, lend = m, lendsv = lend;
        l1 = m + 1;
        if (lend == l) continue;

        float anorm = 0.f;
        for (int i = l; i <= lend; ++i) anorm = fmaxf(anorm, fabsf(d[i - 1]));
        for (int i = l; i <= lend - 1; ++i) anorm = fmaxf(anorm, fabsf(e[i - 1]));
        int iscale = 0; float sclto = 1.f;
        if (anorm == 0.f) continue;
        if (anorm > ssfmax) { iscale = 1; sclto = ssfmax; }
        else if (anorm < ssfmin) { iscale = 2; sclto = ssfmin; }
        if (iscale) {
            float mul = sclto / anorm;
            for (int i = l; i <= lend; ++i) d[i - 1] *= mul;
            for (int i = l; i <= lend - 1; ++i) e[i - 1] *= mul;
        }
        if (fabsf(d[lend - 1]) < fabsf(d[l - 1])) { lend = lsv; l = lendsv; }

        if (lend > l) {
            // QL
            while (true) {
                int mq = lend;
                if (l != lend) {
                    for (int i = l; i <= lend - 1; ++i) {
                        float ei = e[i - 1];
                        float tst = ei * ei;
                        if (tst <= (eps2 * fabsf(d[i - 1])) * fabsf(d[i]) + safmin) { mq = i; break; }
                    }
                }
                if (mq < lend) e[mq - 1] = 0.f;
                float p = d[l - 1];
                if (mq == l) { d[l - 1] = p; l = l + 1; if (l <= lend) continue; break; }
                if (mq == l + 1) {
                    float rt1, rt2, c, s;
                    f_slaev2(d[l - 1], e[l - 1], d[l], &rt1, &rt2, &c, &s);
                    for (int i = 0; i < 3; ++i) {
                        float temp = z[i][l];
                        z[i][l]     = c * temp - s * z[i][l - 1];
                        z[i][l - 1] = s * temp + c * z[i][l - 1];
                    }
                    d[l - 1] = rt1; d[l] = rt2; e[l - 1] = 0.f;
                    l += 2; if (l <= lend) continue; break;
                }
                if (jtot == nmaxit) break;
                jtot++;
                float g = (d[l] - p) / (2.f * e[l - 1]);
                float r = f_slapy2(g, 1.f);
                g = d[mq - 1] - p + e[l - 1] / (g + copysignf(r, g));
                float s = 1.f, c = 1.f; p = 0.f;
                float cw[2], sw[2];
                for (int i = mq - 1; i >= l; --i) {
                    float f = s * e[i - 1];
                    float b = c * e[i - 1];
                    f_slartg(g, f, &c, &s, &r);
                    if (i != mq - 1) e[i] = r;
                    g = d[i] - p;
                    r = (d[i - 1] - g) * s + 2.f * c * b;
                    p = s * r;
                    d[i] = g + p;
                    g = c * r - b;
                    cw[i - l] = c; sw[i - l] = -s;
                }
                for (int j = mq - l; j >= 1; --j) {
                    float cj = cw[j - 1], sj = sw[j - 1];
                    int c0 = l - 1 + (j - 1);
                    for (int i = 0; i < 3; ++i) {
                        float temp = z[i][c0 + 1];
                        z[i][c0 + 1] = cj * temp - sj * z[i][c0];
                        z[i][c0]     = sj * temp + cj * z[i][c0];
                    }
                }
                d[l - 1] -= p;
                e[l - 1] = g;
            }
        } else {
            // QR
            while (true) {
                int mq = lend;
                if (l != lend) {
                    for (int i = l; i >= lend + 1; --i) {
                        float ei = e[i - 2];
                        float tst = ei * ei;
                        if (tst <= (eps2 * fabsf(d[i - 1])) * fabsf(d[i - 2]) + safmin) { mq = i; break; }
                    }
                }
                if (mq > lend) e[mq - 2] = 0.f;
                float p = d[l - 1];
                if (mq == l) { d[l - 1] = p; l = l - 1; if (l >= lend) continue; break; }
                if (mq == l - 1) {
                    float rt1, rt2, c, s;
                    f_slaev2(d[l - 2], e[l - 2], d[l - 1], &rt1, &rt2, &c, &s);
                    for (int i = 0; i < 3; ++i) {
                        float temp = z[i][l - 1];
                        z[i][l - 1] = c * temp - s * z[i][l - 2];
                        z[i][l - 2] = s * temp + c * z[i][l - 2];
                    }
                    d[l - 2] = rt1; d[l - 1] = rt2; e[l - 2] = 0.f;
                    l -= 2; if (l >= lend) continue; break;
                }
                if (jtot == nmaxit) break;
                jtot++;
                float g = (d[l - 2] - p) / (2.f * e[l - 2]);
                float r = f_slapy2(g, 1.f);
                g = d[mq - 1] - p + e[l - 2] / (g + copysignf(r, g));
                float s = 1.f, c = 1.f; p = 0.f;
                float cw[2], sw[2];
                for (int i = mq; i <= l - 1; ++i) {
                    float f = s * e[i - 1];
                    float b = c * e[i - 1];
                    f_slartg(g, f, &c, &s, &r);
                    if (i != mq) e[i - 2] = r;
                    g = d[i - 1] - p;
                    r = (d[i] - g) * s + 2.f * c * b;
                    p = s * r;
                    d[i - 1] = g + p;
                    g = c * r - b;
                    cw[i - mq] = c; sw[i - mq] = s;
                }
                for (int j = 1; j <= l - mq; ++j) {
                    float cj = cw[j - 1], sj = sw[j - 1];
                    int c0 = mq - 1 + (j - 1);
                    for (int i = 0; i < 3; ++i) {
                        float temp = z[i][c0 + 1];
                        z[i][c0 + 1] = cj * temp - sj * z[i][c0];
                        z[i][c0]     = sj * temp + cj * z[i][c0];
                    }
                }
                d[l - 1] -= p;
                e[l - 2] = g;
            }
        }
        if (iscale) {
            float mul = anorm / sclto;
            for (int i = lsv; i <= lendsv; ++i) d[i - 1] *= mul;
            for (int i = lsv; i <= lendsv - 1; ++i) e[i - 1] *= mul;
        }
        if (jtot >= nmaxit) break;
    }

    // sort ascending (column swaps — no sign change)
    for (int ii = 2; ii <= 3; ++ii) {
        int i = ii - 1, k = i;
        float p = d[i - 1];
        for (int j = ii; j <= 3; ++j) if (d[j - 1] < p) { k = j; p = d[j - 1]; }
        if (k != i) {
            d[k - 1] = d[i - 1]; d[i - 1] = p;
            for (int r = 0; r < 3; ++r) { float t = z[r][i - 1]; z[r][i - 1] = z[r][k - 1]; z[r][k - 1] = t; }
        }
    }
    // sormtr('L','L','N')
    float r0 = z[0][0], r1 = z[1][0], r2 = z[2][0];
    if (tau != 0.f) {
        float sum = r1 + v2 * r2;
        r1 -= tau * sum;
        r2 -= tau * (v2 * sum);
    }
    *ox = r0; *oy = r1; *oz = r2;
}

// ---------------- common ----------------

__device__ __forceinline__ float dot_rn(float ax, float ay, float az,
                                        float bx, float by, float bz) {
    return __fadd_rn(__fadd_rn(__fmul_rn(ax, bx), __fmul_rn(ay, by)), __fmul_rn(az, bz));
}

__device__ __forceinline__ unsigned spread7(unsigned v) {
    v &= 0x7Fu;
    v = (v | (v << 16)) & 0x030000FFu;
    v = (v | (v << 8))  & 0x0300F00Fu;
    v = (v | (v << 4))  & 0x030C30C3u;
    v = (v | (v << 2))  & 0x09249249u;
    return v;
}

// ---------------- sort kernel ----------------
// Bitonic sort in LDS with padded indices (i + i/32) to break power-of-2
// stride bank conflicts.
#define SP(i) ((i) + ((i) >> 5))

__global__ __launch_bounds__(1024) void sort_kernel(
    const float* __restrict__ pred, const float* __restrict__ gt,
    float4* __restrict__ mort4, unsigned short* __restrict__ midx)
{
    __shared__ unsigned sk[NP + (NP >> 5)];
    int bc = blockIdx.x;
    int cloud = bc >> 3, b = bc & 7;
    const float* src = (cloud ? gt : pred) + (size_t)b * NP * 3;
    int tid = threadIdx.x;

    for (int t = tid; t < NP; t += 1024) {
        float x = src[3 * t], y = src[3 * t + 1], z = src[3 * t + 2];
        unsigned ix = (unsigned)fminf(fmaxf(x, 0.f) * 128.f, 127.f);
        unsigned iy = (unsigned)fminf(fmaxf(y, 0.f) * 128.f, 127.f);
        unsigned iz = (unsigned)fminf(fmaxf(z, 0.f) * 128.f, 127.f);
        unsigned morton = (spread7(ix) << 2) | (spread7(iy) << 1) | spread7(iz);
        sk[SP(t)] = (morton << 11) | (unsigned)t;
    }
    __syncthreads();
    for (unsigned k = 2; k <= NP; k <<= 1) {
        for (unsigned j = k >> 1; j > 0; j >>= 1) {
            for (int t = tid; t < NP; t += 1024) {
                unsigned ixj = (unsigned)t ^ j;
                if (ixj > (unsigned)t) {
                    unsigned a = sk[SP(t)], c = sk[SP(ixj)];
                    bool up = (((unsigned)t & k) == 0);
                    if ((a > c) == up) { sk[SP(t)] = c; sk[SP(ixj)] = a; }
                }
            }
            __syncthreads();
        }
    }
    float4* out4 = mort4 + (size_t)bc * NP;
    unsigned short* oix = midx + (size_t)bc * NP;
    for (int t = tid; t < NP; t += 1024) {
        unsigned oi = sk[SP(t)] & 0x7FFu;
        float x = src[3 * oi], y = src[3 * oi + 1], z = src[3 * oi + 2];
        out4[t] = make_float4(x, y, z, dot_rn(x, y, z, x, y, z));
        oix[t] = (unsigned short)oi;
    }
}

// ---------------- scan kernel ----------------
// 512 blocks x 512 threads (8 waves). Block = tile of 64 Morton-adjacent
// queries. Wave w scans candidates jj = (tileStart + 8t + w) mod 2048.
// Heap SEEDED with the 16 slice candidates at t in [-4,12) (skipped in main
// loop) -> tight initial kmax -> __any branch mostly skips. Seed sets are
// subsets of each wave's own slice (disjoint across waves), so the merged
// union still contains the exact global top-16. Keys pack ORIGINAL index;
// d2 is reference-exact -> selection bit-identical to R4-R6.
#define KIDX(s, w, l) (((s) * 8 + (w)) * 64 + (l))
#define TSEED 16      // seed count = KN
#define TSKIP 12      // main loop covers t = TSKIP .. TSKIP+239 (window [-4,12))

__global__ __launch_bounds__(512) void scan_kernel(
    const float* __restrict__ pred, const float* __restrict__ gt,
    const float4* __restrict__ mort4, const unsigned short* __restrict__ midx,
    float* __restrict__ nP, float* __restrict__ nG, double* __restrict__ acc)
{
    __shared__ float4 sHome[NP];            // morton-ordered home (x,y,z,|p|^2)  32 KB
    __shared__ float sO[3][NP];             // morton-ordered other x,y,z planes  24 KB
    __shared__ unsigned short sOrig[NP];    // home morton-pos -> original idx     4 KB
    unsigned* kbuf = (unsigned*)sHome;      // post-scan alias: [16][8][64] u32 = 32 KB
    float* mbuf = (float*)sOrig;            // post-scan alias: 8*64 floats = 2 KB
    float* cache = &sO[0][0];               // tail alias: 48*64 floats = 12 KB

    int bi = blockIdx.x;
    bool predHome = bi < NB * 32;
    int lb = predHome ? bi : bi - NB * 32;
    int b = lb >> 5;
    int tile = lb & 31;
    int tid  = threadIdx.x;
    int wave = tid >> 6;
    int lane = tid & 63;
    int homeSel = predHome ? 0 : 1;

    const float* home = (predHome ? pred : gt) + (size_t)b * NP * 3;
    const float4* mh = mort4 + (size_t)(homeSel * NB + b) * NP;
    const float4* mo = mort4 + (size_t)((1 - homeSel) * NB + b) * NP;
    const unsigned short* mi = midx + (size_t)(homeSel * NB + b) * NP;

    for (int t = tid; t < NP; t += 512) {
        sHome[t] = mh[t];
        float4 o = mo[t];
        sO[0][t] = o.x; sO[1][t] = o.y; sO[2][t] = o.z;
        sOrig[t] = mi[t];
    }
    __syncthreads();

    int im = tile * 64 + lane;              // morton position of this query
    float4 q = sHome[im];
    float qx = q.x, qy = q.y, qz = q.z, qq = q.w;
    unsigned qoi = sOrig[im];               // original index (for normal output)
    int tileStart = tile * 64;

    // --- seed heap with 16 real slice candidates near the tile (t in [-4,12)) ---
    unsigned keys[KN];
    float minv = 1e30f;
    #pragma unroll
    for (int s = 0; s < TSEED; ++s) {
        int t = (s + 256 - 4) & 255;                           // -4..11 mod 256
        int jj = (tileStart + ((t << 3) | wave)) & (NP - 1);
        float4 h = sHome[jj];
        float dotj = dot_rn(qx, qy, qz, h.x, h.y, h.z);
        float d2 = __fsub_rn(__fadd_rn(qq, h.w), __fmul_rn(2.f, dotj));
        keys[s] = (__float_as_uint(d2) & 0xFFFFF800u) | (unsigned)sOrig[jj];
        float ex = qx - sO[0][jj], ey = qy - sO[1][jj], ez = qz - sO[2][jj];
        minv = fminf(minv, fmaf(ex, ex, fmaf(ey, ey, ez * ez)));
    }
    unsigned kmax = keys[0];
    #pragma unroll
    for (int s = 1; s < KN; ++s) kmax = keys[s] > kmax ? keys[s] : kmax;

    auto insertKey = [&](unsigned key) {
        if (__any(key < kmax)) {            // wave-uniform scalar branch
            if (key < kmax) {               // per-lane predication inside
                #pragma unroll
                for (int s = 0; s < KN; ++s) keys[s] = (keys[s] == kmax) ? key : keys[s];
                unsigned m = keys[0];
                #pragma unroll
                for (int s = 1; s < KN; ++s) m = keys[s] > m ? keys[s] : m;
                kmax = m;
            }
        }
    };

    // --- main scan: t = TSKIP .. TSKIP+239 (seed window excluded) ---
    for (int u = 0; u < 256 - TSEED; ++u) {
        int t = u + TSKIP;                                     // 12..251, no wrap
        int jj = (tileStart + ((t << 3) | wave)) & (NP - 1);
        float4 h = sHome[jj];                                  // broadcast b128
        float dotj = dot_rn(qx, qy, qz, h.x, h.y, h.z);
        float d2 = __fsub_rn(__fadd_rn(qq, h.w), __fmul_rn(2.f, dotj));
        unsigned oi = sOrig[jj];                               // broadcast u16
        insertKey((__float_as_uint(d2) & 0xFFFFF800u) | oi);
        float ex = qx - sO[0][jj], ey = qy - sO[1][jj], ez = qz - sO[2][jj];
        minv = fminf(minv, fmaf(ex, ex, fmaf(ey, ey, ez * ez)));
    }
    __syncthreads();   // all sHome/sO/sOrig reads done before aliasing writes

    // publish partials (conflict-free transposed layout)
    #pragma unroll
    for (int s = 0; s < KN; ++s) kbuf[KIDX(s, wave, lane)] = keys[s];
    mbuf[wave * 64 + lane] = minv;
    __syncthreads();

    // tree merge: 8 -> 4 -> 2 -> 1 (disjoint candidate sets; order-invariant)
    if (wave < 4) {
        #pragma unroll
        for (int s = 0; s < KN; ++s) insertKey(kbuf[KIDX(s, wave + 4, lane)]);
        minv = fminf(minv, mbuf[(wave + 4) * 64 + lane]);
        #pragma unroll
        for (int s = 0; s < KN; ++s) kbuf[KIDX(s, wave, lane)] = keys[s];
        mbuf[wave * 64 + lane] = minv;
    }
    __syncthreads();
    if (wave < 2) {
        #pragma unroll
        for (int s = 0; s < KN; ++s) insertKey(kbuf[KIDX(s, wave + 2, lane)]);
        minv = fminf(minv, mbuf[(wave + 2) * 64 + lane]);
        #pragma unroll
        for (int s = 0; s < KN; ++s) kbuf[KIDX(s, wave, lane)] = keys[s];
        mbuf[wave * 64 + lane] = minv;
    }
    __syncthreads();
    if (wave != 0) return;

    #pragma unroll
    for (int s = 0; s < KN; ++s) insertKey(kbuf[KIDX(s, 1, lane)]);
    minv = fminf(minv, mbuf[64 + lane]);

    // --- gather neighbors by ORIGINAL index from global (L2-hot), cache in LDS ---
    float sx = 0.f, sy = 0.f, sz = 0.f;
    #pragma unroll
    for (int s = 0; s < KN; ++s) {
        const float* hp = home + 3 * (size_t)(keys[s] & 0x7FFu);
        float px = hp[0], py = hp[1], pz = hp[2];
        cache[(s * 3 + 0) * 64 + lane] = px;
        cache[(s * 3 + 1) * 64 + lane] = py;
        cache[(s * 3 + 2) * 64 + lane] = pz;
        sx += px; sy += py; sz += pz;
    }
    float mx = sx * (1.0f / KN), my = sy * (1.0f / KN), mz = sz * (1.0f / KN);
    float cxx = 0.f, cxy = 0.f, cxz = 0.f, cyy = 0.f, cyz = 0.f, czz = 0.f;
    #pragma unroll
    for (int s = 0; s < KN; ++s) {
        float ax = cache[(s * 3 + 0) * 64 + lane] - mx;
        float ay = cache[(s * 3 + 1) * 64 + lane] - my;
        float az = cache[(s * 3 + 2) * 64 + lane] - mz;
        cxx += ax * ax; cxy += ax * ay; cxz += ax * az;
        cyy += ay * ay; cyz += ay * az; czz += az * az;
    }
    cxx *= (1.f / KN); cxy *= (1.f / KN); cxz *= (1.f / KN);
    cyy *= (1.f / KN); cyz *= (1.f / KN); czz *= (1.f / KN);

    // --- repulsion: 4 nearest excluding self (pred side only); destroys keys ---
    float rep = 0.0f;
    if (predHome) {
        #pragma unroll
        for (int r = 0; r < 5; ++r) {
            unsigned m = keys[0];
            #pragma unroll
            for (int s = 1; s < KN; ++s) m = keys[s] < m ? keys[s] : m;
            if (r > 0) {
                float d2 = __uint_as_float(m & 0xFFFFF800u);
                float dd = sqrtf(fmaxf(d2, 1e-12f));
                rep += fmaxf(0.02f - dd, 0.0f);
            }
            #pragma unroll
            for (int s = 0; s < KN; ++s) keys[s] = (keys[s] == m) ? 0xFFFFFFFFu : keys[s];
        }
    }

    // --- normal via faithful ssyevd emulation ---
    float nx, ny, nz;
    ssyevd3_evec0(cxx, cxy, cxz, cyy, cyz, czz, &nx, &ny, &nz);

    float* nout = predHome ? nP : nG;
    int gi = b * NP + (int)qoi;
    nout[gi * 3 + 0] = nx;
    nout[gi * 3 + 1] = ny;
    nout[gi * 3 + 2] = nz;

    double part = (double)minv * (1.0 / (NB * NP))
                + (double)rep  * (0.1 / (NB * NP * 4));

    #pragma unroll
    for (int off = 32; off > 0; off >>= 1) part += __shfl_down(part, off);
    if (lane == 0) atomicAdd(acc, part);
}

// ---------------------------------------------------------------------------
// Fused normal-dot + finalize: single block, runs after scan (stream order).
__global__ __launch_bounds__(1024) void dotfin_kernel(
    const float* __restrict__ nP, const float* __restrict__ nG,
    const double* __restrict__ acc, float* __restrict__ out)
{
    int tid = threadIdx.x;
    float s = 0.f;
    for (int i = tid; i < NB * NP; i += 1024)
        s += nP[3 * i] * nG[3 * i] + nP[3 * i + 1] * nG[3 * i + 1] + nP[3 * i + 2] * nG[3 * i + 2];
    double part = (double)s;
    #pragma unroll
    for (int off = 32; off > 0; off >>= 1) part += __shfl_down(part, off);
    __shared__ double w[16];
    if ((tid & 63) == 0) w[tid >> 6] = part;
    __syncthreads();
    if (tid == 0) {
        double t = 0.0;
        for (int k = 0; k < 16; ++k) t += w[k];
        out[0] = (float)(acc[0] - t * (0.01 / (NB * NP)) + 0.01);
    }
}

// ---------------------------------------------------------------------------
extern "C" void kernel_launch(void* const* d_in, const int* in_sizes, int n_in,
                              void* d_out, int out_size, void* d_ws, size_t ws_size,
                              hipStream_t stream)
{
    const float* pred = (const float*)d_in[0];
    const float* gt   = (const float*)d_in[1];

    // ws layout: acc(64) | mort4 (524288) | midx (65536) | nP | nG
    char* base = (char*)d_ws;
    double* acc = (double*)base;
    float4* mort4 = (float4*)(base + 64);
    unsigned short* midx = (unsigned short*)(base + 64 + 524288);
    float* nP = (float*)(base + 64 + 524288 + 65536);
    float* nG = nP + (size_t)NB * NP * 3;

    hipMemsetAsync(d_ws, 0, 64, stream);
    sort_kernel<<<dim3(16), dim3(1024), 0, stream>>>(pred, gt, mort4, midx);
    scan_kernel<<<dim3(NB * 32 * 2), dim3(512), 0, stream>>>(pred, gt, mort4, midx, nP, nG, acc);
    dotfin_kernel<<<dim3(1), dim3(1024), 0, stream>>>(nP, nG, acc, (float*)d_out);
}

// Round 8
// 169.106 us; speedup vs baseline: 3.2874x; 1.2049x over previous
//
#include <hip/hip_runtime.h>

// CombinedLoss: chamfer(pred,gt) + 0.1*repulsion(pred,k=4) + 0.01*(1 - mean(n_pred . n_gt))
// B=8, N=2048, fp32 in, fp32 scalar out.
// Normals match np.linalg.eigh (LAPACK ssyevd) signs point-by-point via faithful
// fp32 ssytd2+ssteqr+sormtr emulation (R3-R7: absmax 0.0).
// R8: branchless sorted-chain top-10 per wave-slice (insert = 20 min/max, no
// branch: R5-R7 showed any-lane insert prob ~= 1, so the branch never skips),
// exact top-16 via 8x10 pool merge + violation-detect + rare rescan fallback
// (P ~= 2.6e-7/slice-query). Morton sort DELETED (only served branch coherence).

#define NB 8
#define NP 2048
#define KW 10     // per-slice kept keys
#define KN 16

// ---------------- LAPACK helpers (fp32, faithful — DO NOT TOUCH) ----------------

__device__ __forceinline__ float f_slapy2(float x, float y) {
    float xa = fabsf(x), ya = fabsf(y);
    float w = fmaxf(xa, ya), zm = fminf(xa, ya);
    if (zm == 0.f) return w;
    float q = zm / w;
    return w * sqrtf(1.f + q * q);
}

// LAPACK >=3.10 slartg convention: c >= 0 always.
__device__ __forceinline__ void f_slartg(float f, float g, float* cs, float* sn, float* r) {
    if (g == 0.f) { *cs = 1.f; *sn = 0.f; *r = f; }
    else if (f == 0.f) { *cs = 0.f; *sn = copysignf(1.f, g); *r = fabsf(g); }
    else {
        float d = sqrtf(__fadd_rn(__fmul_rn(f, f), __fmul_rn(g, g)));
        *cs = fabsf(f) / d;
        *r  = copysignf(d, f);
        *sn = g / *r;
    }
}

__device__ void f_slaev2(float a, float b, float c,
                         float* rt1, float* rt2, float* cs1, float* sn1) {
    float sm = a + c;
    float df = a - c;
    float adf = fabsf(df);
    float tb = b + b;
    float ab = fabsf(tb);
    float acmx, acmn;
    if (fabsf(a) > fabsf(c)) { acmx = a; acmn = c; } else { acmx = c; acmn = a; }
    float rt;
    if (adf > ab)      { float q = ab / adf; rt = adf * sqrtf(1.f + q * q); }
    else if (adf < ab) { float q = adf / ab; rt = ab * sqrtf(1.f + q * q); }
    else               rt = ab * sqrtf(2.f);
    int sgn1;
    if (sm < 0.f) {
        *rt1 = 0.5f * (sm - rt); sgn1 = -1;
        *rt2 = (acmx / *rt1) * acmn - (b / *rt1) * b;
    } else if (sm > 0.f) {
        *rt1 = 0.5f * (sm + rt); sgn1 = 1;
        *rt2 = (acmx / *rt1) * acmn - (b / *rt1) * b;
    } else {
        *rt1 = 0.5f * rt; *rt2 = -0.5f * rt; sgn1 = 1;
    }
    float cs; int sgn2;
    if (df >= 0.f) { cs = df + rt; sgn2 = 1; }
    else           { cs = df - rt; sgn2 = -1; }
    float acs = fabsf(cs);
    if (acs > ab) {
        float ct = -tb / cs;
        *sn1 = 1.f / sqrtf(1.f + ct * ct);
        *cs1 = ct * *sn1;
    } else {
        if (ab == 0.f) { *cs1 = 1.f; *sn1 = 0.f; }
        else {
            float tn = -cs / tb;
            *cs1 = 1.f / sqrtf(1.f + tn * tn);
            *sn1 = tn * *cs1;
        }
    }
    if (sgn1 == sgn2) { float tn = *cs1; *cs1 = -*sn1; *sn1 = tn; }
}

// fp32 ssyevd for a 3x3 symmetric matrix (lower triangle given), returns
// eigenvector of the SMALLEST eigenvalue, with LAPACK's sign convention.
__device__ void ssyevd3_evec0(float a00, float a10, float a20,
                              float a11, float a21, float a22,
                              float* ox, float* oy, float* oz) {
    // ---- ssytd2('L') ----
    float d[3], e[2];
    float tau = 0.f, v2 = 0.f;
    float xnorm = fabsf(a20);
    if (xnorm == 0.f) {
        tau = 0.f;
        d[0] = a00; d[1] = a11; d[2] = a22; e[0] = a10; e[1] = a21;
    } else {
        float beta = -copysignf(f_slapy2(a10, xnorm), a10);
        tau = (beta - a10) / beta;
        float inv = 1.f / (a10 - beta);
        v2 = a20 * inv;
        float x1 = tau * (a11 + a21 * v2);
        float x2 = tau * (a21 + a22 * v2);
        float alpha = -0.5f * tau * (x1 + x2 * v2);
        float w1 = x1 + alpha;
        float w2 = x2 + alpha * v2;
        float b11 = a11 - 2.f * w1;
        float b21 = a21 - v2 * w1 - w2;
        float b22 = a22 - 2.f * (v2 * w2);
        d[0] = a00; d[1] = b11; d[2] = b22; e[0] = beta; e[1] = b21;
    }
    // ---- ssteqr('I', n=3) ----
    const float eps    = 5.9604645e-08f;
    const float eps2   = eps * eps;
    const float safmin = 1.1754944e-38f;
    const float ssfmax = sqrtf(1.f / safmin) / 3.f;
    const float ssfmin = sqrtf(safmin) / eps2;
    const int n = 3, nmaxit = 90;
    float z[3][3] = {{1.f,0.f,0.f},{0.f,1.f,0.f},{0.f,0.f,1.f}};
    int jtot = 0;
    int l1 = 1;

    while (true) {
        if (l1 > n) break;
        if (l1 > 1) e[l1 - 2] = 0.f;
        int m = n;
        for (int mi = l1; mi <= n - 1; ++mi) {
            float tst = fabsf(e[mi - 1]);
            if (tst == 0.f) { m = mi; break; }
            if (tst <= (sqrtf(fabsf(d[mi - 1])) * sqrtf(fabsf(d[mi]))) * eps) {
                e[mi - 1] = 0.f; m = mi; break;
            }
        }
        int l = l1, lsv = l, lend = m, lendsv = lend;
        l1 = m + 1;
        if (lend == l) continue;

        float anorm = 0.f;
        for (int i = l; i <= lend; ++i) anorm = fmaxf(anorm, fabsf(d[i - 1]));
        for (int i = l; i <= lend - 1; ++i) anorm = fmaxf(anorm, fabsf(e[i - 1]));
        int iscale = 0; float sclto = 1.f;
        if (anorm == 0.f) continue;
        if (anorm > ssfmax) { iscale = 1; sclto = ssfmax; }
        else if (anorm < ssfmin) { iscale = 2; sclto = ssfmin; }
        if (iscale) {
            float mul = sclto / anorm;
            for (int i = l; i <= lend; ++i) d[i - 1] *= mul;
            for (int i = l; i <= lend - 1; ++i) e[i - 1] *= mul;
        }
        if (fabsf(d[lend - 1]) < fabsf(d[l - 1])) { lend = lsv; l = lendsv; }

        if (lend > l) {
            // QL
            while (true) {
                int mq = lend;
                if (l != lend) {
                    for (int i = l; i <= lend - 1; ++i) {
                        float ei = e[i - 1];
                        float tst = ei * ei;
                        if (tst <= (eps2 * fabsf(d[i - 1])) * fabsf(d[i]) + safmin) { mq = i; break; }
                    }
                }
                if (mq < lend) e[mq - 1] = 0.f;
                float p = d[l - 1];
                if (mq == l) { d[l - 1] = p; l = l + 1; if (l <= lend) continue; break; }
                if (mq == l + 1) {
                    float rt1, rt2, c, s;
                    f_slaev2(d[l - 1], e[l - 1], d[l], &rt1, &rt2, &c, &s);
                    for (int i = 0; i < 3; ++i) {
                        float temp = z[i][l];
                        z[i][l]     = c * temp - s * z[i][l - 1];
                        z[i][l - 1] = s * temp + c * z[i][l - 1];
                    }
                    d[l - 1] = rt1; d[l] = rt2; e[l - 1] = 0.f;
                    l += 2; if (l <= lend) continue; break;
                }
                if (jtot == nmaxit) break;
                jtot++;
                float g = (d[l] - p) / (2.f * e[l - 1]);
                float r = f_slapy2(g, 1.f);
                g = d[mq - 1] - p + e[l - 1] / (g + copysignf(r, g));
                float s = 1.f, c = 1.f; p = 0.f;
                float cw[2], sw[2];
                for (int i = mq - 1; i >= l; --i) {
                    float f = s * e[i - 1];
                    float b = c * e[i - 1];
                    f_slartg(g, f, &c, &s, &r);
                    if (i != mq - 1) e[i] = r;
                    g = d[i] - p;
                    r = (d[i - 1] - g) * s + 2.f * c * b;
                    p = s * r;
                    d[i] = g + p;
                    g = c * r - b;
                    cw[i - l] = c; sw[i - l] = -s;
                }
                for (int j = mq - l; j >= 1; --j) {
                    float cj = cw[j - 1], sj = sw[j - 1];
                    int c0 = l - 1 + (j - 1);
                    for (int i = 0; i < 3; ++i) {
                        float temp = z[i][c0 + 1];
                        z[i][c0 + 1] = cj * temp - sj * z[i][c0];
                        z[i][c0]     = sj * temp + cj * z[i][c0];
                    }
                }
                d[l - 1] -= p;
                e[l - 1] = g;
            }
        } else {
            // QR
            while (true) {
                int mq = lend;
                if (l != lend) {
                    for (int i = l; i >= lend + 1; --i) {
                        float ei = e[i - 2];
                        float tst = ei * ei;
                        if (tst <= (eps2 * fabsf(d[i - 1])) * fabsf(d[i - 2]) + safmin) { mq = i; break; }
                    }
                }
                if (mq > lend) e[mq - 2] = 0.f;
                float p = d[l - 1];
                if (mq == l) { d[l - 1] = p; l = l - 1; if (l >= lend) continue; break; }
                if (mq == l - 1) {
                    float rt1, rt2, c, s;
                    f_slaev2(d[l - 2], e[l - 2], d[l - 1], &rt1, &rt2, &c, &s);
                    for (int i = 0; i < 3; ++i) {
                        float temp = z[i][l - 1];
                        z[i][l - 1] = c * temp - s * z[i][l - 2];
                        z[i][l - 2] = s * temp + c * z[i][l - 2];
                    }
                    d[l - 2] = rt1; d[l - 1] = rt2; e[l - 2] = 0.f;
                    l -= 2; if (l >= lend) continue; break;
                }
                if (jtot == nmaxit) break;
                jtot++;
                float g = (d[l - 2] - p) / (2.f * e[l - 2]);
                float r = f_slapy2(g, 1.f);
                g = d[mq - 1] - p + e[l - 2] / (g + copysignf(r, g));
                float s = 1.f, c = 1.f; p = 0.f;
                float cw[2], sw[2];
                for (int i = mq; i <= l - 1; ++i) {
                    float f = s * e[i - 1];
                    float b = c * e[i - 1];
                    f_slartg(g, f, &c, &s, &r);
                    if (i != mq) e[i - 2] = r;
                    g = d[i - 1] - p;
                    r = (d[i] - g) * s + 2.f * c * b;
                    p = s * r;
                    d[i - 1] = g + p;
                    g = c * r - b;
                    cw[i - mq] = c; sw[i - mq] = s;
                }
                for (int j = 1; j <= l - mq; ++j) {
                    float cj = cw[j - 1], sj = sw[j - 1];
                    int c0 = mq - 1 + (j - 1);
                    for (int i = 0; i < 3; ++i) {
                        float temp = z[i][c0 + 1];
                        z[i][c0 + 1] = cj * temp - sj * z[i][c0];
                        z[i][c0]     = sj * temp + cj * z[i][c0];
                    }
                }
                d[l - 1] -= p;
                e[l - 2] = g;
            }
        }
        if (iscale) {
            float mul = anorm / sclto;
            for (int i = lsv; i <= lendsv; ++i) d[i - 1] *= mul;
            for (int i = lsv; i <= lendsv - 1; ++i) e[i - 1] *= mul;
        }
        if (jtot >= nmaxit) break;
    }

    // sort ascending (column swaps — no sign change)
    for (int ii = 2; ii <= 3; ++ii) {
        int i = ii - 1, k = i;
        float p = d[i - 1];
        for (int j = ii; j <= 3; ++j) if (d[j - 1] < p) { k = j; p = d[j - 1]; }
        if (k != i) {
            d[k - 1] = d[i - 1]; d[i - 1] = p;
            for (int r = 0; r < 3; ++r) { float t = z[r][i - 1]; z[r][i - 1] = z[r][k - 1]; z[r][k - 1] = t; }
        }
    }
    // sormtr('L','L','N')
    float r0 = z[0][0], r1 = z[1][0], r2 = z[2][0];
    if (tau != 0.f) {
        float sum = r1 + v2 * r2;
        r1 -= tau * sum;
        r2 -= tau * (v2 * sum);
    }
    *ox = r0; *oy = r1; *oz = r2;
}

// ---------------- common ----------------

__device__ __forceinline__ float dot_rn(float ax, float ay, float az,
                                        float bx, float by, float bz) {
    return __fadd_rn(__fadd_rn(__fmul_rn(ax, bx), __fmul_rn(ay, by)), __fmul_rn(az, bz));
}

// Branchless sorted-chain inserts: keys ascending; drops the largest.
__device__ __forceinline__ void chain10(unsigned k[KW], unsigned x) {
    unsigned t = x;
    #pragma unroll
    for (int s = 0; s < KW; ++s) {
        unsigned lo = k[s] < t ? k[s] : t;
        unsigned hi = k[s] < t ? t : k[s];
        k[s] = lo; t = hi;
    }
}
__device__ __forceinline__ void chain16(unsigned k[KN], unsigned x) {
    unsigned t = x;
    #pragma unroll
    for (int s = 0; s < KN; ++s) {
        unsigned lo = k[s] < t ? k[s] : t;
        unsigned hi = k[s] < t ? t : k[s];
        k[s] = lo; t = hi;
    }
}

// ---------------- scan kernel ----------------
// 512 blocks x 512 threads (8 waves). Block = tile of 64 queries (original
// order). Wave w scans interleaved slice j = 8t+w keeping a branchless sorted
// top-10; merged 80-key pool contains the exact top-16 unless one slice held
// >=11 of them (P~2.6e-7) — detected via (slice 10th-best < pool 16th) and
// repaired by an exact slice rescan. Keys: (d2bits & ~0x7FF) | j, ref-exact d2.
#define KIDX(s, w, l) (((s) * 8 + (w)) * 64 + (l))

__global__ __launch_bounds__(512) void scan_kernel(
    const float* __restrict__ pred, const float* __restrict__ gt,
    float* __restrict__ nP, float* __restrict__ nG, double* __restrict__ acc)
{
    __shared__ float4 sHome[NP];            // (x,y,z,|p|^2)  32 KB — stays live (fallback)
    __shared__ float4 sOther[NP];           // (x,y,z,0)      32 KB — aliased post-scan
    unsigned* kbuf = (unsigned*)sOther;                       // [10][8][64] u32 = 20 KB
    float* mbuf = (float*)((char*)sOther + 20480);            // [8][64] f32 = 2 KB
    float* cache = (float*)sOther;                            // tail (post-fallback): 12 KB

    int bi = blockIdx.x;
    bool predHome = bi < NB * 32;
    int lb = predHome ? bi : bi - NB * 32;
    int b = lb >> 5;
    int tile = lb & 31;
    int tid  = threadIdx.x;
    int wave = tid >> 6;
    int lane = tid & 63;

    const float* home  = (predHome ? pred : gt) + (size_t)b * NP * 3;
    const float* other = (predHome ? gt : pred) + (size_t)b * NP * 3;

    for (int t = tid; t < NP; t += 512) {
        float hx = home[3 * t], hy = home[3 * t + 1], hz = home[3 * t + 2];
        sHome[t] = make_float4(hx, hy, hz, dot_rn(hx, hy, hz, hx, hy, hz));
        float ox = other[3 * t], oy = other[3 * t + 1], oz = other[3 * t + 2];
        sOther[t] = make_float4(ox, oy, oz, 0.f);
    }
    __syncthreads();

    int im = tile * 64 + lane;              // original index of this query
    float4 q = sHome[im];
    float qx = q.x, qy = q.y, qz = q.z, qq = q.w;

    unsigned keys[KW];
    #pragma unroll
    for (int s = 0; s < KW; ++s) keys[s] = 0x7F800000u | (unsigned)s;  // sorted inf seeds

    float minv = 1e30f;

    for (int t = 0; t < NP / 8; ++t) {
        int jj = (t << 3) | wave;
        float4 h = sHome[jj];                                  // broadcast b128
        float dotj = dot_rn(qx, qy, qz, h.x, h.y, h.z);
        float d2 = __fsub_rn(__fadd_rn(qq, h.w), __fmul_rn(2.f, dotj));
        chain10(keys, (__float_as_uint(d2) & 0xFFFFF800u) | (unsigned)jj);
        float4 o = sOther[jj];                                 // broadcast b128
        float ex = qx - o.x, ey = qy - o.y, ez = qz - o.z;
        minv = fminf(minv, fmaf(ex, ex, fmaf(ey, ey, ez * ez)));
    }
    __syncthreads();   // all sOther reads done before kbuf aliasing writes

    // publish per-wave sorted top-10 + chamfer partial min
    #pragma unroll
    for (int s = 0; s < KW; ++s) kbuf[KIDX(s, wave, lane)] = keys[s];
    mbuf[wave * 64 + lane] = minv;
    __syncthreads();

    if (wave != 0) return;

    // --- merge 8x10 -> sorted top-16 ---
    unsigned k16[KN];
    #pragma unroll
    for (int s = 0; s < KW; ++s) k16[s] = keys[s];             // own sorted 10
    #pragma unroll
    for (int s = KW; s < KN; ++s) k16[s] = 0x7F800000u | (unsigned)s;  // seeds (> any real)
    for (int w = 1; w < 8; ++w) {
        #pragma unroll
        for (int s = 0; s < KW; ++s) chain16(k16, kbuf[KIDX(s, w, lane)]);
    }
    minv = fminf(fminf(fminf(mbuf[lane], mbuf[64 + lane]),
                       fminf(mbuf[128 + lane], mbuf[192 + lane])),
                 fminf(fminf(mbuf[256 + lane], mbuf[320 + lane]),
                       fminf(mbuf[384 + lane], mbuf[448 + lane])));

    // --- violation detect: slice may hide a top-16 member iff its 10th-best
    //     (kbuf slot 9, sorted) < pool 16th (k16[15]). Exact repair below. ---
    unsigned flags = 0;
    #pragma unroll
    for (int w = 0; w < 8; ++w)
        flags |= (kbuf[KIDX(KW - 1, w, lane)] < k16[15]) ? (1u << w) : 0u;

    if (__any(flags != 0)) {                 // ~0.07 expected events per LAUNCH
        #pragma unroll
        for (int s = 0; s < KN; ++s)
            k16[s] = flags ? (0x7F800000u | (unsigned)s) : k16[s];   // reinit flagged lanes
        for (int w = 0; w < 8; ++w) {
            #pragma unroll
            for (int s = 0; s < KW; ++s) {
                unsigned kk = kbuf[KIDX(s, w, lane)];
                bool use = (flags != 0) && !((flags >> w) & 1);
                chain16(k16, use ? kk : 0xFFFFFFFFu);          // inf = no-op
            }
        }
        for (int w = 0; w < 8; ++w) {
            if (__any((flags >> w) & 1)) {
                bool actw = ((flags >> w) & 1) != 0;
                for (int t = 0; t < NP / 8; ++t) {
                    int jj = (t << 3) | w;
                    float4 h = sHome[jj];
                    float dotj = dot_rn(qx, qy, qz, h.x, h.y, h.z);
                    float d2 = __fsub_rn(__fadd_rn(qq, h.w), __fmul_rn(2.f, dotj));
                    unsigned key = (__float_as_uint(d2) & 0xFFFFF800u) | (unsigned)jj;
                    chain16(k16, actw ? key : 0xFFFFFFFFu);
                }
            }
        }
    }

    // --- repulsion: k16 sorted ascending, slot 0 = self (d2=0) -> slots 1..4 ---
    float rep = 0.0f;
    if (predHome) {
        #pragma unroll
        for (int r = 1; r <= 4; ++r) {
            float d2 = __uint_as_float(k16[r] & 0xFFFFF800u);
            float dd = sqrtf(fmaxf(d2, 1e-12f));
            rep += fmaxf(0.02f - dd, 0.0f);
        }
    }

    // --- covariance over the 16-NN (gather by index from global, L2-hot) ---
    float sx = 0.f, sy = 0.f, sz = 0.f;
    #pragma unroll
    for (int s = 0; s < KN; ++s) {
        const float* hp = home + 3 * (size_t)(k16[s] & 0x7FFu);
        float px = hp[0], py = hp[1], pz = hp[2];
        cache[(s * 3 + 0) * 64 + lane] = px;
        cache[(s * 3 + 1) * 64 + lane] = py;
        cache[(s * 3 + 2) * 64 + lane] = pz;
        sx += px; sy += py; sz += pz;
    }
    float mx = sx * (1.0f / KN), my = sy * (1.0f / KN), mz = sz * (1.0f / KN);
    float cxx = 0.f, cxy = 0.f, cxz = 0.f, cyy = 0.f, cyz = 0.f, czz = 0.f;
    #pragma unroll
    for (int s = 0; s < KN; ++s) {
        float ax = cache[(s * 3 + 0) * 64 + lane] - mx;
        float ay = cache[(s * 3 + 1) * 64 + lane] - my;
        float az = cache[(s * 3 + 2) * 64 + lane] - mz;
        cxx += ax * ax; cxy += ax * ay; cxz += ax * az;
        cyy += ay * ay; cyz += ay * az; czz += az * az;
    }
    cxx *= (1.f / KN); cxy *= (1.f / KN); cxz *= (1.f / KN);
    cyy *= (1.f / KN); cyz *= (1.f / KN); czz *= (1.f / KN);

    // --- normal via faithful ssyevd emulation ---
    float nx, ny, nz;
    ssyevd3_evec0(cxx, cxy, cxz, cyy, cyz, czz, &nx, &ny, &nz);

    float* nout = predHome ? nP : nG;
    int gi = b * NP + im;
    nout[gi * 3 + 0] = nx;
    nout[gi * 3 + 1] = ny;
    nout[gi * 3 + 2] = nz;

    double part = (double)minv * (1.0 / (NB * NP))
                + (double)rep  * (0.1 / (NB * NP * 4));

    #pragma unroll
    for (int off = 32; off > 0; off >>= 1) part += __shfl_down(part, off);
    if (lane == 0) atomicAdd(acc, part);
}

// ---------------------------------------------------------------------------
// Fused normal-dot + finalize: single block, runs after scan (stream order).
__global__ __launch_bounds__(1024) void dotfin_kernel(
    const float* __restrict__ nP, const float* __restrict__ nG,
    const double* __restrict__ acc, float* __restrict__ out)
{
    int tid = threadIdx.x;
    float s = 0.f;
    for (int i = tid; i < NB * NP; i += 1024)
        s += nP[3 * i] * nG[3 * i] + nP[3 * i + 1] * nG[3 * i + 1] + nP[3 * i + 2] * nG[3 * i + 2];
    double part = (double)s;
    #pragma unroll
    for (int off = 32; off > 0; off >>= 1) part += __shfl_down(part, off);
    __shared__ double w[16];
    if ((tid & 63) == 0) w[tid >> 6] = part;
    __syncthreads();
    if (tid == 0) {
        double t = 0.0;
        for (int k = 0; k < 16; ++k) t += w[k];
        out[0] = (float)(acc[0] - t * (0.01 / (NB * NP)) + 0.01);
    }
}

// ---------------------------------------------------------------------------
extern "C" void kernel_launch(void* const* d_in, const int* in_sizes, int n_in,
                              void* d_out, int out_size, void* d_ws, size_t ws_size,
                              hipStream_t stream)
{
    const float* pred = (const float*)d_in[0];
    const float* gt   = (const float*)d_in[1];

    // ws layout: acc(64) | nP | nG
    char* base = (char*)d_ws;
    double* acc = (double*)base;
    float* nP = (float*)(base + 64);
    float* nG = nP + (size_t)NB * NP * 3;

    hipMemsetAsync(d_ws, 0, 64, stream);
    scan_kernel<<<dim3(NB * 32 * 2), dim3(512), 0, stream>>>(pred, gt, nP, nG, acc);
    dotfin_kernel<<<dim3(1), dim3(1024), 0, stream>>>(nP, nG, acc, (float*)d_out);
}